// Round 8
// baseline (319.580 us; speedup 1.0000x reference)
//
#include <hip/hip_runtime.h>
#include <hip/hip_fp16.h>
#include <cmath>
#include <cstdint>

// Problem constants (fixed by the reference).
constexpr int P  = 2000, M = 150, DG = 2000, F = 256, H = 4, DH = 64;
constexpr int N1 = P + M;          // 2150
constexpr int N2 = P + DG;         // 4000
constexpr int E1 = 137600, E2 = 256000, EGP = 64000, EGM = 4800;
constexpr int SA_HID = 128;

// Edge-range offsets for the fused build kernel.
constexpr int HO1 = E1, HO2 = E1 + E2, HO3 = HO2 + EGP, HO4 = HO3 + EGP,
              HO5 = HO4 + EGM, HOE = HO5 + EGM;   // 531200 total edges

// ELL capacities (overflow list guarantees correctness regardless).
constexpr int CAP_A = 160;
constexpr int CAP_G = 96;
constexpr int OVF_CAP = 4096;

// One counter per 64B line (R7: removed same-line atomic serialization).
constexpr int CPAD = 16;

// ---- fp16 helpers -----------------------------------------------------------
__device__ __forceinline__ float4 h4_to_f4(const __half* p) {
  union { ushort4 u4; __half2 h2[2]; } u;
  u.u4 = *(const ushort4*)p;
  float2 lo = __half22float2(u.h2[0]);
  float2 hi = __half22float2(u.h2[1]);
  return make_float4(lo.x, lo.y, hi.x, hi.y);
}
__device__ __forceinline__ void f4_to_h4(__half* p, float4 v) {
  union { ushort4 u4; __half2 h2[2]; } u;
  u.h2[0] = __float22half2_rn(make_float2(v.x, v.y));
  u.h2[1] = __float22half2_rn(make_float2(v.z, v.w));
  *(ushort4*)p = u.u4;
}

// ---------------------------------------------------------------------------
// ELL build (R7 padded-counter structure) + FUSED fp32->fp16 embed cast.
// The cast is independent streaming work hidden under the scatter's atomic
// latency (build was <1% VALUBusy with idle load pipes).
// ---------------------------------------------------------------------------
constexpr int CAST_CH = (P * F + M * F + DG * F) / 8;   // 8-float chunks

__global__ __launch_bounds__(256) void k_build(
    const int* __restrict__ a1r, const int* __restrict__ a1c, const float* __restrict__ a1v,
    const int* __restrict__ a2r, const int* __restrict__ a2c, const float* __restrict__ a2v,
    const int* __restrict__ d0, const int* __restrict__ s0,
    const int* __restrict__ d1, const int* __restrict__ s1,
    const int* __restrict__ d2, const int* __restrict__ s2,
    const int* __restrict__ d3, const int* __restrict__ s3,
    int* cur1, uint2* ell1, int* cur2, uint2* ell2,
    int* cu0, unsigned* eg0, int* cu1, unsigned* eg1,
    int* cu2, unsigned* eg2, int* cu3, unsigned* eg3,
    int* __restrict__ ovf_n, int4* __restrict__ ovf,
    const float* __restrict__ pEf, const float* __restrict__ mEf,
    const float* __restrict__ dEf,
    __half* __restrict__ pEh, __half* __restrict__ mEh, __half* __restrict__ dEh) {
  int tid = blockIdx.x * 256 + threadIdx.x;
  int T = gridDim.x * 256;
  int seg[4], row[4]; unsigned p0[4], p1[4];
#pragma unroll
  for (int u = 0; u < 4; ++u) {
    int i = tid + u * T;
    seg[u] = -1;
    if (i < HOE) {
      if (i < HO1)      { seg[u] = 0; row[u] = a1r[i]; p0[u] = (unsigned)a1c[i]; p1[u] = __float_as_uint(a1v[i]); }
      else if (i < HO2) { int j = i - HO1; seg[u] = 1; row[u] = a2r[j]; p0[u] = (unsigned)a2c[j]; p1[u] = __float_as_uint(a2v[j]); }
      else if (i < HO3) { int j = i - HO2; seg[u] = 2; row[u] = d0[j]; p0[u] = (unsigned)s0[j]; }
      else if (i < HO4) { int j = i - HO3; seg[u] = 3; row[u] = d1[j]; p0[u] = (unsigned)s1[j]; }
      else if (i < HO5) { int j = i - HO4; seg[u] = 4; row[u] = d2[j]; p0[u] = (unsigned)s2[j]; }
      else              { int j = i - HO5; seg[u] = 5; row[u] = d3[j]; p0[u] = (unsigned)s3[j]; }
    }
  }
#pragma unroll
  for (int u = 0; u < 4; ++u) {
    int r = row[u];
    switch (seg[u]) {
      case 0: { int slot = atomicAdd(&cur1[(size_t)r * CPAD], 1);
        if (slot < CAP_A) ell1[(size_t)r * CAP_A + slot] = make_uint2(p0[u], p1[u]);
        else { int o = atomicAdd(&ovf_n[0], 1); if (o < OVF_CAP) ovf[0 * OVF_CAP + o] = make_int4(r, (int)p0[u], (int)p1[u], 0); } } break;
      case 1: { int slot = atomicAdd(&cur2[(size_t)r * CPAD], 1);
        if (slot < CAP_A) ell2[(size_t)r * CAP_A + slot] = make_uint2(p0[u], p1[u]);
        else { int o = atomicAdd(&ovf_n[1], 1); if (o < OVF_CAP) ovf[1 * OVF_CAP + o] = make_int4(r, (int)p0[u], (int)p1[u], 0); } } break;
      case 2: { int slot = atomicAdd(&cu0[(size_t)r * CPAD], 1);
        if (slot < CAP_G) eg0[(size_t)r * CAP_G + slot] = p0[u];
        else { int o = atomicAdd(&ovf_n[2], 1); if (o < OVF_CAP) ovf[2 * OVF_CAP + o] = make_int4(r, (int)p0[u], 0, 0); } } break;
      case 3: { int slot = atomicAdd(&cu1[(size_t)r * CPAD], 1);
        if (slot < CAP_G) eg1[(size_t)r * CAP_G + slot] = p0[u];
        else { int o = atomicAdd(&ovf_n[3], 1); if (o < OVF_CAP) ovf[3 * OVF_CAP + o] = make_int4(r, (int)p0[u], 0, 0); } } break;
      case 4: { int slot = atomicAdd(&cu2[(size_t)r * CPAD], 1);
        if (slot < CAP_G) eg2[(size_t)r * CAP_G + slot] = p0[u];
        else { int o = atomicAdd(&ovf_n[4], 1); if (o < OVF_CAP) ovf[4 * OVF_CAP + o] = make_int4(r, (int)p0[u], 0, 0); } } break;
      case 5: { int slot = atomicAdd(&cu3[(size_t)r * CPAD], 1);
        if (slot < CAP_G) eg3[(size_t)r * CAP_G + slot] = p0[u];
        else { int o = atomicAdd(&ovf_n[5], 1); if (o < OVF_CAP) ovf[5 * OVF_CAP + o] = make_int4(r, (int)p0[u], 0, 0); } } break;
      default: break;
    }
  }
  // Fused embed cast fp32 -> fp16 (independent of the scatter above).
  for (int c = tid; c < CAST_CH; c += T) {
    int j = c * 8;
    const float* src; __half* dst;
    if (j < P * F)              { src = pEf + j;               dst = pEh + j; }
    else if (j < P * F + M * F) { src = mEf + (j - P * F);     dst = mEh + (j - P * F); }
    else                        { src = dEf + (j - P*F - M*F); dst = dEh + (j - P*F - M*F); }
    float4 a = *(const float4*)src, b = *(const float4*)(src + 4);
    f4_to_h4(dst, a);
    f4_to_h4(dst + 4, b);
  }
}

// ---------------------------------------------------------------------------
// SPMM: wave-per-row over ELL, fp16 GATHERS (halved bytes), fp32 accumulate.
// LAYER 1: gathers fp16 embeds, writes lat fp32 (own-row path) + fp16 (gather
// path). LAYER 2: gathers fp16 lat, acc = fp32 lat[row] + s; writes acc +
// m_gcn/d_gcn slices. Both graphs per dispatch.
// ---------------------------------------------------------------------------
template<int LAYER>
__global__ __launch_bounds__(256) void k_spmm(
    const int* __restrict__ cur1, const uint2* __restrict__ ell1,
    const int* __restrict__ cur2, const uint2* __restrict__ ell2,
    const int* __restrict__ ovf_n, const int4* __restrict__ ovf,
    const __half* __restrict__ pEh, const __half* __restrict__ mEh,
    const __half* __restrict__ dEh,
    float* __restrict__ lat1f, float* __restrict__ lat2f,
    __half* __restrict__ lat1h, __half* __restrict__ lat2h,
    float* __restrict__ acc1, float* __restrict__ acc2,
    float* __restrict__ out_mgcn, float* __restrict__ out_dgcn) {
  int gw = (blockIdx.x * 256 + threadIdx.x) >> 6;
  if (gw >= N1 + N2) return;
  int lane = threadIdx.x & 63;
  bool g2 = gw >= N1;
  int row = g2 ? gw - N1 : gw;
  const uint2* pe = (g2 ? ell2 : ell1) + (size_t)row * CAP_A;
  const __half* latinh = g2 ? lat2h : lat1h;
  const __half* tailEh = g2 ? dEh : mEh;
  int deg = (g2 ? cur2 : cur1)[(size_t)row * CPAD];
  int dn = deg < CAP_A ? deg : CAP_A;
  int fo = lane << 2;                       // offset in elements (4 per lane)
  float4 s = {0.f, 0.f, 0.f, 0.f};
  auto fetch = [&](int c) -> float4 {
    const __half* b;
    if (LAYER == 1) b = (c < P) ? (pEh + (size_t)c * F) : (tailEh + (size_t)(c - P) * F);
    else            b = latinh + (size_t)c * F;
    return h4_to_f4(b + fo);
  };
  int i = 0;
  for (; i + 8 <= dn; i += 8) {
    uint2 m[8]; float4 a[8];
#pragma unroll
    for (int u = 0; u < 8; ++u) m[u] = pe[i + u];
#pragma unroll
    for (int u = 0; u < 8; ++u) a[u] = fetch((int)m[u].x);
#pragma unroll
    for (int u = 0; u < 8; ++u) {
      float v = __uint_as_float(m[u].y);
      s.x += v * a[u].x; s.y += v * a[u].y; s.z += v * a[u].z; s.w += v * a[u].w;
    }
  }
  for (; i + 4 <= dn; i += 4) {
    uint2 m0 = pe[i], m1 = pe[i + 1], m2 = pe[i + 2], m3 = pe[i + 3];
    float v0 = __uint_as_float(m0.y), v1 = __uint_as_float(m1.y),
          v2 = __uint_as_float(m2.y), v3 = __uint_as_float(m3.y);
    float4 a0 = fetch((int)m0.x), a1 = fetch((int)m1.x),
           a2 = fetch((int)m2.x), a3 = fetch((int)m3.x);
    s.x += v0 * a0.x + v1 * a1.x + v2 * a2.x + v3 * a3.x;
    s.y += v0 * a0.y + v1 * a1.y + v2 * a2.y + v3 * a3.y;
    s.z += v0 * a0.z + v1 * a1.z + v2 * a2.z + v3 * a3.z;
    s.w += v0 * a0.w + v1 * a1.w + v2 * a2.w + v3 * a3.w;
  }
  for (; i < dn; ++i) {
    uint2 m = pe[i];
    float v = __uint_as_float(m.y);
    float4 a = fetch((int)m.x);
    s.x += v * a.x; s.y += v * a.y; s.z += v * a.z; s.w += v * a.w;
  }
  // Overflow edges (normally zero).
  {
    int gi = g2 ? 1 : 0;
    int on = ovf_n[gi];
    if (on > 0) {
      const int4* ol = ovf + gi * OVF_CAP;
      for (int k = 0; k < on; ++k) {
        int4 e = ol[k];
        if (e.x == row) {
          float v = __int_as_float(e.z);
          float4 a = fetch(e.y);
          s.x += v * a.x; s.y += v * a.y; s.z += v * a.z; s.w += v * a.w;
        }
      }
    }
  }
  float4 l;
  l.x = s.x > 0.f ? s.x : 0.5f * s.x;
  l.y = s.y > 0.f ? s.y : 0.5f * s.y;
  l.z = s.z > 0.f ? s.z : 0.5f * s.z;
  l.w = s.w > 0.f ? s.w : 0.5f * s.w;
  if (LAYER == 1) {
    *(float4*)((g2 ? lat2f : lat1f) + (size_t)row * F + fo) = l;   // exact own-row
    f4_to_h4((g2 ? lat2h : lat1h) + (size_t)row * F + fo, l);      // gather copy
  } else {
    const float* latf = g2 ? lat2f : lat1f;
    float4 b = *(const float4*)(latf + (size_t)row * F + fo);
    float4 a = {b.x + l.x, b.y + l.y, b.z + l.z, b.w + l.w};
    *(float4*)((g2 ? acc2 : acc1) + (size_t)row * F + fo) = a;
    if (row >= P)
      *(float4*)((g2 ? out_dgcn : out_mgcn) + (size_t)(row - P) * F + fo) = a;
  }
}

// ---------------------------------------------------------------------------
// All 4 GAT feature GEMMs in one dispatch. FR=16 rows/block (halves the
// per-block W re-read vs FR=8). feat stored fp16 for the agg gather.
// ---------------------------------------------------------------------------
constexpr int FR  = 16;
constexpr int NB0 = (P + FR - 1) / FR;   // 125
constexpr int NB2 = (M + FR - 1) / FR;   // 10
constexpr int FEAT_BLOCKS = 2 * NB0 + 2 * NB2;

__global__ __launch_bounds__(256) void k_gat_feat_all(
    const float* __restrict__ acc1, const float* __restrict__ acc2,
    const float* __restrict__ gat_W, const float* __restrict__ gat_al,
    const float* __restrict__ gat_ar,
    __half* __restrict__ f0, __half* __restrict__ f1,
    __half* __restrict__ f2, __half* __restrict__ f3,
    float* __restrict__ el, float* __restrict__ er) {
  int b = blockIdx.x;
  int g, rb, n; const float* h; __half* fout;
  if (b < NB0)            { g = 0; rb = b;              n = P; h = acc1; fout = f0; }
  else if (b < 2 * NB0)   { g = 1; rb = b - NB0;        n = P; h = acc2; fout = f1; }
  else if (b < 2*NB0+NB2) { g = 2; rb = b - 2 * NB0;    n = M; h = acc1 + (size_t)P * F; fout = f2; }
  else                    { g = 3; rb = b - 2*NB0 - NB2; n = M; h = acc1 + (size_t)P * F; fout = f3; }
  int elo = (g == 0) ? 0 : (g == 1) ? P * H : (g == 2) ? 2 * P * H : (2 * P + M) * H;
  const float* W = gat_W + (size_t)g * F * F;
  __shared__ float hs[FR][F];
  int t = threadIdx.x;
  int r0 = rb * FR;
  for (int q = t; q < FR * 64; q += 256) {
    int r = q >> 6, ln = q & 63;
    int row = r0 + r;
    float4 v = {0.f, 0.f, 0.f, 0.f};
    if (row < n) v = *(const float4*)(h + (size_t)row * F + (ln << 2));
    *(float4*)&hs[r][ln << 2] = v;
  }
  __syncthreads();
  float acc[FR];
#pragma unroll
  for (int r = 0; r < FR; ++r) acc[r] = 0.f;
  for (int k = 0; k < F; k += 4) {
    float w0 = W[(size_t)k * F + t],       w1 = W[(size_t)(k + 1) * F + t],
          w2 = W[(size_t)(k + 2) * F + t], w3 = W[(size_t)(k + 3) * F + t];
#pragma unroll
    for (int r = 0; r < FR; ++r) {
      float4 h4 = *(const float4*)&hs[r][k];
      acc[r] += h4.x * w0 + h4.y * w1 + h4.z * w2 + h4.w * w3;
    }
  }
  int head = t >> 6, d = t & 63;           // one wave == one head
  float av = gat_al[g * H * DH + head * DH + d];
  float rv = gat_ar[g * H * DH + head * DH + d];
#pragma unroll
  for (int r = 0; r < FR; ++r) {
    int row = r0 + r;
    if (row < n) {
      fout[(size_t)row * F + t] = __float2half_rn(acc[r]);
      float cl = acc[r] * av, cr = acc[r] * rv;
      for (int o = 32; o > 0; o >>= 1) {
        cl += __shfl_down(cl, o, 64);
        cr += __shfl_down(cr, o, 64);
      }
      if (d == 0) { el[elo + row * H + head] = cl; er[elo + row * H + head] = cr; }
    }
  }
}

// ---------------------------------------------------------------------------
// All 4 GAT aggregations in one dispatch: wave-per-dst-row over ELL, fp16
// feat gathers. Fused max + exp-sum + weighted aggregation + bias + ELU.
// ---------------------------------------------------------------------------
__global__ __launch_bounds__(256) void k_gat_agg_all(
    const int* __restrict__ cu0, const unsigned* __restrict__ eg0,
    const int* __restrict__ cu1, const unsigned* __restrict__ eg1,
    const int* __restrict__ cu2, const unsigned* __restrict__ eg2,
    const int* __restrict__ cu3, const unsigned* __restrict__ eg3,
    const int* __restrict__ ovf_n, const int4* __restrict__ ovf,
    const float* __restrict__ el, const float* __restrict__ er,
    const __half* __restrict__ f0, const __half* __restrict__ f1,
    const __half* __restrict__ f2, const __half* __restrict__ f3,
    const float* __restrict__ gat_b,
    float* __restrict__ e0, float* __restrict__ e1,
    float* __restrict__ e2, float* __restrict__ e3) {
  int gw = (blockIdx.x * 256 + threadIdx.x) >> 6;
  if (gw >= 2 * P + 2 * M) return;
  int lane = threadIdx.x & 63;
  int g, row; const int* cu; const unsigned* eg; const __half* feat; float* out; int elo;
  if (gw < P)            { g = 0; row = gw;             cu = cu0; eg = eg0; feat = f0; out = e0; elo = 0; }
  else if (gw < 2 * P)   { g = 1; row = gw - P;         cu = cu1; eg = eg1; feat = f1; out = e1; elo = P * H; }
  else if (gw < 2*P + M) { g = 2; row = gw - 2 * P;     cu = cu2; eg = eg2; feat = f2; out = e2; elo = 2 * P * H; }
  else                   { g = 3; row = gw - 2 * P - M; cu = cu3; eg = eg3; feat = f3; out = e3; elo = (2 * P + M) * H; }
  int head = lane >> 4;
  int fo = lane << 2;
  const float* elb = el + elo;
  float erv = er[elo + row * H + head];
  int deg = cu[(size_t)row * CPAD];
  int dn = deg < CAP_G ? deg : CAP_G;
  const unsigned* ps = eg + (size_t)row * CAP_G;
  int on = ovf_n[2 + g];
  const int4* ol = ovf + (2 + g) * OVF_CAP;
  float mx = -3.4e38f;
  int i = 0;
  for (; i + 4 <= dn; i += 4) {
    int s0 = (int)ps[i], s1 = (int)ps[i + 1], s2 = (int)ps[i + 2], s3 = (int)ps[i + 3];
    float a = elb[s0 * H + head] + erv, b = elb[s1 * H + head] + erv,
          c = elb[s2 * H + head] + erv, d = elb[s3 * H + head] + erv;
    a = a > 0.f ? a : 0.2f * a; b = b > 0.f ? b : 0.2f * b;
    c = c > 0.f ? c : 0.2f * c; d = d > 0.f ? d : 0.2f * d;
    mx = fmaxf(mx, fmaxf(fmaxf(a, b), fmaxf(c, d)));
  }
  for (; i < dn; ++i) {
    float a = elb[(int)ps[i] * H + head] + erv;
    a = a > 0.f ? a : 0.2f * a;
    mx = fmaxf(mx, a);
  }
  if (on > 0) {
    for (int k = 0; k < on; ++k) {
      int4 e = ol[k];
      if (e.x == row) {
        float a = elb[e.y * H + head] + erv;
        a = a > 0.f ? a : 0.2f * a;
        mx = fmaxf(mx, a);
      }
    }
  }
  float ssum = 0.f;
  float4 acc = {0.f, 0.f, 0.f, 0.f};
  i = 0;
  for (; i + 2 <= dn; i += 2) {
    int s0 = (int)ps[i], s1 = (int)ps[i + 1];
    float a = elb[s0 * H + head] + erv; a = a > 0.f ? a : 0.2f * a;
    float b = elb[s1 * H + head] + erv; b = b > 0.f ? b : 0.2f * b;
    float x0 = expf(a - mx), x1 = expf(b - mx);
    float4 q0 = h4_to_f4(feat + (size_t)s0 * F + fo);
    float4 q1 = h4_to_f4(feat + (size_t)s1 * F + fo);
    ssum += x0 + x1;
    acc.x += x0 * q0.x + x1 * q1.x;
    acc.y += x0 * q0.y + x1 * q1.y;
    acc.z += x0 * q0.z + x1 * q1.z;
    acc.w += x0 * q0.w + x1 * q1.w;
  }
  for (; i < dn; ++i) {
    int s0 = (int)ps[i];
    float a = elb[s0 * H + head] + erv; a = a > 0.f ? a : 0.2f * a;
    float x0 = expf(a - mx);
    float4 q0 = h4_to_f4(feat + (size_t)s0 * F + fo);
    ssum += x0;
    acc.x += x0 * q0.x; acc.y += x0 * q0.y; acc.z += x0 * q0.z; acc.w += x0 * q0.w;
  }
  if (on > 0) {
    for (int k = 0; k < on; ++k) {
      int4 e = ol[k];
      if (e.x == row) {
        float a = elb[e.y * H + head] + erv; a = a > 0.f ? a : 0.2f * a;
        float x0 = expf(a - mx);
        float4 q0 = h4_to_f4(feat + (size_t)e.y * F + fo);
        ssum += x0;
        acc.x += x0 * q0.x; acc.y += x0 * q0.y; acc.z += x0 * q0.z; acc.w += x0 * q0.w;
      }
    }
  }
  float inv = 1.f / (ssum + 1e-9f);
  const float* bb = gat_b + g * F + fo;
  float4 v = {acc.x * inv + bb[0], acc.y * inv + bb[1],
              acc.z * inv + bb[2], acc.w * inv + bb[3]};
  v.x = v.x > 0.f ? v.x : expm1f(v.x);
  v.y = v.y > 0.f ? v.y : expm1f(v.y);
  v.z = v.z > 0.f ? v.z : expm1f(v.z);
  v.w = v.w > 0.f ? v.w : expm1f(v.w);
  *(float4*)(out + (size_t)row * F + fo) = v;
}

// ---------------------------------------------------------------------------
// Semantic attention weights for all 4 z-matrices. SR=16 halves W1 re-reads.
// ---------------------------------------------------------------------------
constexpr int SR  = 16;
constexpr int SB0 = (P + SR - 1) / SR;   // 125
constexpr int SB2 = (M + SR - 1) / SR;   // 10
constexpr int SEM_BLOCKS = 2 * SB0 + 2 * SB2;

__global__ __launch_bounds__(128) void k_sem_w_all(
    const float* __restrict__ e0, const float* __restrict__ e1,
    const float* __restrict__ e2, const float* __restrict__ e3,
    const float* __restrict__ W1, const float* __restrict__ b1,
    const float* __restrict__ W2, float* __restrict__ w) {
  int b = blockIdx.x;
  int zid, rb, n; const float* z;
  if (b < SB0)            { zid = 0; rb = b;             n = P; z = e0; }
  else if (b < 2 * SB0)   { zid = 1; rb = b - SB0;       n = P; z = e1; }
  else if (b < 2*SB0+SB2) { zid = 2; rb = b - 2 * SB0;   n = M; z = e2; }
  else                    { zid = 3; rb = b - 2*SB0-SB2; n = M; z = e3; }
  __shared__ float zs[SR][F];
  int t = threadIdx.x;
  int r0 = rb * SR;
  for (int q = t; q < SR * 64; q += 128) {
    int r = q >> 6, ln = q & 63;
    int row = r0 + r;
    float4 v = {0.f, 0.f, 0.f, 0.f};
    if (row < n) v = *(const float4*)(z + (size_t)row * F + (ln << 2));
    *(float4*)&zs[r][ln << 2] = v;
  }
  __syncthreads();
  float hid[SR];
#pragma unroll
  for (int r = 0; r < SR; ++r) hid[r] = b1[t];
  for (int k = 0; k < F; k += 4) {
    float w0 = W1[(size_t)k * SA_HID + t],       w1 = W1[(size_t)(k + 1) * SA_HID + t],
          w2 = W1[(size_t)(k + 2) * SA_HID + t], w3 = W1[(size_t)(k + 3) * SA_HID + t];
#pragma unroll
    for (int r = 0; r < SR; ++r) {
      float4 z4 = *(const float4*)&zs[r][k];
      hid[r] += z4.x * w0 + z4.y * w1 + z4.z * w2 + z4.w * w3;
    }
  }
  float w2v = W2[t];
  float local = 0.f;
  for (int r = 0; r < SR; ++r) {
    int row = r0 + r;
    if (row < n) local += tanhf(hid[r]) * w2v;
  }
  for (int o = 32; o > 0; o >>= 1) local += __shfl_down(local, o, 64);
  __shared__ float pp[2];
  if ((t & 63) == 0) pp[t >> 6] = local;
  __syncthreads();
  if (t == 0) atomicAdd(&w[zid], pp[0] + pp[1]);
}

// ---------------------------------------------------------------------------
// Single-block: med = beta-combine(e2,e3) + on-the-fly relu column-sum, then
// c[m2] = sv . W_bot[:,m2] + M*out_b[m2]. One block -> no cross-block fence.
// ---------------------------------------------------------------------------
__global__ __launch_bounds__(256) void k_med_cvec(
    const float* __restrict__ e2, const float* __restrict__ e3,
    const float* __restrict__ w, const float* __restrict__ outW,
    const float* __restrict__ outb,
    float* __restrict__ out_med, float* __restrict__ cbuf) {
  int t = threadIdx.x;
  float m0 = w[2] * (1.f / M), m1 = w[3] * (1.f / M);
  float mxv = fmaxf(m0, m1);
  float a0 = expf(m0 - mxv), a1 = expf(m1 - mxv);
  float sc = 1.f / (a0 + a1);
  a0 *= sc; a1 *= sc;
  float4 rs = {0.f, 0.f, 0.f, 0.f};
  for (int j = t; j < M * F / 4; j += 256) {
    float4 u0 = ((const float4*)e2)[j], u1 = ((const float4*)e3)[j];
    float4 r = {a0 * u0.x + a1 * u1.x, a0 * u0.y + a1 * u1.y,
                a0 * u0.z + a1 * u1.z, a0 * u0.w + a1 * u1.w};
    ((float4*)out_med)[j] = r;
    rs.x += r.x > 0.f ? r.x : 0.f;
    rs.y += r.y > 0.f ? r.y : 0.f;
    rs.z += r.z > 0.f ? r.z : 0.f;
    rs.w += r.w > 0.f ? r.w : 0.f;
  }
  __shared__ float4 sv4[4][64];
  sv4[t >> 6][t & 63] = rs;
  __syncthreads();
  __shared__ float sv[F];
  if (t < 64) {
    float4 a = sv4[0][t], b = sv4[1][t], c = sv4[2][t], d = sv4[3][t];
    sv[t * 4 + 0] = a.x + b.x + c.x + d.x;
    sv[t * 4 + 1] = a.y + b.y + c.y + d.y;
    sv[t * 4 + 2] = a.z + b.z + c.z + d.z;
    sv[t * 4 + 3] = a.w + b.w + c.w + d.w;
  }
  __syncthreads();
  if (t < M) {
    float cc = (float)M * outb[t];
    for (int f = 0; f < F; f += 4) {
      cc += sv[f]     * outW[(size_t)(F + f) * M + t]
          + sv[f + 1] * outW[(size_t)(F + f + 1) * M + t]
          + sv[f + 2] * outW[(size_t)(F + f + 2) * M + t]
          + sv[f + 3] * outW[(size_t)(F + f + 3) * M + t];
    }
    cbuf[t] = cc;
  }
}

// ---------------------------------------------------------------------------
// Final: patient beta-combine fused with simi GEMM.
// ---------------------------------------------------------------------------
constexpr int FIN_R = 8;   // P % FIN_R == 0
__global__ __launch_bounds__(256) void k_final(
    const float* __restrict__ e0, const float* __restrict__ e1,
    const float* __restrict__ w, const float* __restrict__ outW,
    const float* __restrict__ c,
    float* __restrict__ out_pat, float* __restrict__ simi) {
  float m0 = w[0] * (1.f / P), m1 = w[1] * (1.f / P);
  float mxv = fmaxf(m0, m1);
  float a0 = expf(m0 - mxv), a1 = expf(m1 - mxv);
  float sc = 1.f / (a0 + a1);
  a0 *= sc; a1 *= sc;
  __shared__ float psh[FIN_R][F];
  int t = threadIdx.x;
  int r0 = blockIdx.x * FIN_R;
  for (int q = t; q < FIN_R * 64; q += 256) {
    int r = q >> 6, ln = q & 63;
    size_t off = (size_t)(r0 + r) * F + (ln << 2);
    float4 u0 = *(const float4*)(e0 + off), u1 = *(const float4*)(e1 + off);
    float4 v = {a0 * u0.x + a1 * u1.x, a0 * u0.y + a1 * u1.y,
                a0 * u0.z + a1 * u1.z, a0 * u0.w + a1 * u1.w};
    *(float4*)(out_pat + off) = v;
    v.x = v.x > 0.f ? v.x : 0.f; v.y = v.y > 0.f ? v.y : 0.f;
    v.z = v.z > 0.f ? v.z : 0.f; v.w = v.w > 0.f ? v.w : 0.f;
    *(float4*)&psh[r][ln << 2] = v;
  }
  __syncthreads();
  if (t < M) {
    float acc[FIN_R];
#pragma unroll
    for (int r = 0; r < FIN_R; ++r) acc[r] = 0.f;
    for (int f = 0; f < F; f += 4) {
      float w0 = outW[(size_t)f * M + t],       w1 = outW[(size_t)(f + 1) * M + t],
            w2 = outW[(size_t)(f + 2) * M + t], w3 = outW[(size_t)(f + 3) * M + t];
#pragma unroll
      for (int r = 0; r < FIN_R; ++r) {
        float4 p4 = *(const float4*)&psh[r][f];
        acc[r] += p4.x * w0 + p4.y * w1 + p4.z * w2 + p4.w * w3;
      }
    }
    float cv = c[t];
    for (int r = 0; r < FIN_R; ++r)
      simi[(size_t)(r0 + r) * M + t] = (float)M * acc[r] + cv;
  }
}

// ---------------------------------------------------------------------------
extern "C" void kernel_launch(void* const* d_in, const int* in_sizes, int n_in,
                              void* d_out, int out_size, void* d_ws, size_t ws_size,
                              hipStream_t stream) {
  const int*   adj1_rows = (const int*)d_in[0];
  const int*   adj1_cols = (const int*)d_in[1];
  const float* adj1_vals = (const float*)d_in[2];
  const int*   adj2_rows = (const int*)d_in[3];
  const int*   adj2_cols = (const int*)d_in[4];
  const float* adj2_vals = (const float*)d_in[5];
  const int*   g0_src = (const int*)d_in[6];
  const int*   g0_dst = (const int*)d_in[7];
  const int*   g1_src = (const int*)d_in[8];
  const int*   g1_dst = (const int*)d_in[9];
  const int*   g2_src = (const int*)d_in[10];
  const int*   g2_dst = (const int*)d_in[11];
  const int*   g3_src = (const int*)d_in[12];
  const int*   g3_dst = (const int*)d_in[13];
  // d_in[14] = keepRate (unused, == 1)
  const float* pE     = (const float*)d_in[15];
  const float* mE     = (const float*)d_in[16];
  const float* dE     = (const float*)d_in[17];
  const float* gat_W  = (const float*)d_in[18];
  const float* gat_al = (const float*)d_in[19];
  const float* gat_ar = (const float*)d_in[20];
  const float* gat_b  = (const float*)d_in[21];
  const float* sa_W1  = (const float*)d_in[22];
  const float* sa_b1  = (const float*)d_in[23];
  const float* sa_W2  = (const float*)d_in[24];
  const float* out_W  = (const float*)d_in[25];
  const float* out_b  = (const float*)d_in[26];

  // ---- workspace layout: [zeroed (padded counters) | ELL | fp16 | fp32] ----
  int* ip = (int*)d_ws;
  int* cur1 = ip; ip += (size_t)N1 * CPAD;
  int* cur2 = ip; ip += (size_t)N2 * CPAD;
  int* cu0  = ip; ip += (size_t)P * CPAD;
  int* cu1  = ip; ip += (size_t)P * CPAD;
  int* cu2  = ip; ip += (size_t)M * CPAD;
  int* cu3  = ip; ip += (size_t)M * CPAD;
  int* ovf_n = ip; ip += 6;
  float* wbuf = (float*)ip; ip += 4;
  size_t memset_bytes = (size_t)((char*)ip - (char*)d_ws);

  uintptr_t up = ((uintptr_t)ip + 15) & ~(uintptr_t)15;
  int4* ovf = (int4*)up;                       // 6 * OVF_CAP
  uint2* ell1 = (uint2*)(ovf + 6 * OVF_CAP);   // N1 * CAP_A
  uint2* ell2 = ell1 + (size_t)N1 * CAP_A;     // N2 * CAP_A
  unsigned* eg0 = (unsigned*)(ell2 + (size_t)N2 * CAP_A);
  unsigned* eg1 = eg0 + (size_t)P * CAP_G;
  unsigned* eg2 = eg1 + (size_t)P * CAP_G;
  unsigned* eg3 = eg2 + (size_t)M * CAP_G;
  // fp16 region (16B-aligned by construction: all preceding counts even)
  __half* hp = (__half*)(eg3 + (size_t)M * CAP_G);
  __half* pEh   = hp; hp += (size_t)P * F;
  __half* mEh   = hp; hp += (size_t)M * F;
  __half* dEh   = hp; hp += (size_t)DG * F;
  __half* lat1h = hp; hp += (size_t)N1 * F;
  __half* lat2h = hp; hp += (size_t)N2 * F;
  __half* f0h   = hp; hp += (size_t)P * F;
  __half* f1h   = hp; hp += (size_t)P * F;
  __half* f2h   = hp; hp += (size_t)M * F;
  __half* f3h   = hp; hp += (size_t)M * F;
  float* fp = (float*)hp;
  float* lat1f = fp; fp += (size_t)N1 * F;
  float* lat2f = fp; fp += (size_t)N2 * F;
  float* acc1  = fp; fp += (size_t)N1 * F;
  float* acc2  = fp; fp += (size_t)N2 * F;
  float* el    = fp; fp += (size_t)(2 * P + 2 * M) * H;
  float* er    = fp; fp += (size_t)(2 * P + 2 * M) * H;
  float* e0b   = fp; fp += (size_t)P * F;
  float* e1b   = fp; fp += (size_t)P * F;
  float* e2b   = fp; fp += (size_t)M * F;
  float* e3b   = fp; fp += (size_t)M * F;
  float* cbuf  = fp; fp += 256;

  // ---- output layout: (simi_pm, d_gcn, med, m_gcn, patient) ----
  float* out_simi = (float*)d_out;               // P*M
  float* out_dgcn = out_simi + (size_t)P * M;    // DG*F
  float* out_med  = out_dgcn + (size_t)DG * F;   // M*F
  float* out_mgcn = out_med  + (size_t)M * F;    // M*F
  float* out_pat  = out_mgcn + (size_t)M * F;    // P*F

  // ---- zero padded counters (~540 KB) ----
  hipMemsetAsync(d_ws, 0, memset_bytes, stream);

  // ---- ELL build + fused fp16 embed cast: ONE dispatch ----
  int eb = ((HOE + 3) / 4 + 255) / 256;
  k_build<<<eb, 256, 0, stream>>>(adj1_rows, adj1_cols, adj1_vals,
                                  adj2_rows, adj2_cols, adj2_vals,
                                  g0_dst, g0_src, g1_dst, g1_src,
                                  g2_dst, g2_src, g3_dst, g3_src,
                                  cur1, ell1, cur2, ell2,
                                  cu0, eg0, cu1, eg1, cu2, eg2, cu3, eg3,
                                  ovf_n, ovf,
                                  pE, mE, dE, pEh, mEh, dEh);

  // ---- GNN: 2 fused layers (both graphs per dispatch), fp16 gathers ----
  int sb = ((N1 + N2) * 64 + 255) / 256;
  k_spmm<1><<<sb, 256, 0, stream>>>(cur1, ell1, cur2, ell2, ovf_n, ovf,
                                    pEh, mEh, dEh, lat1f, lat2f, lat1h, lat2h,
                                    acc1, acc2, out_mgcn, out_dgcn);
  k_spmm<2><<<sb, 256, 0, stream>>>(cur1, ell1, cur2, ell2, ovf_n, ovf,
                                    pEh, mEh, dEh, lat1f, lat2f, lat1h, lat2h,
                                    acc1, acc2, out_mgcn, out_dgcn);

  // ---- 4 GATs: 2 dispatches ----
  k_gat_feat_all<<<FEAT_BLOCKS, 256, 0, stream>>>(acc1, acc2, gat_W, gat_al, gat_ar,
                                                  f0h, f1h, f2h, f3h, el, er);
  int ab = ((2 * P + 2 * M) * 64 + 255) / 256;
  k_gat_agg_all<<<ab, 256, 0, stream>>>(cu0, eg0, cu1, eg1, cu2, eg2, cu3, eg3,
                                        ovf_n, ovf, el, er, f0h, f1h, f2h, f3h, gat_b,
                                        e0b, e1b, e2b, e3b);

  // ---- semantic attention weights ----
  k_sem_w_all<<<SEM_BLOCKS, 128, 0, stream>>>(e0b, e1b, e2b, e3b, sa_W1, sa_b1, sa_W2, wbuf);

  // ---- med combine + cvec (single block) ----
  k_med_cvec<<<1, 256, 0, stream>>>(e2b, e3b, wbuf, out_W, out_b, out_med, cbuf);

  // ---- final: patient combine + simi GEMM fused ----
  k_final<<<P / FIN_R, 256, 0, stream>>>(e0b, e1b, wbuf, out_W, cbuf, out_pat, out_simi);
}

// Round 9
// 313.947 us; speedup vs baseline: 1.0179x; 1.0179x over previous
//
#include <hip/hip_runtime.h>
#include <hip/hip_fp16.h>
#include <cmath>
#include <cstdint>

// Problem constants (fixed by the reference).
constexpr int P  = 2000, M = 150, DG = 2000, F = 256, H = 4, DH = 64;
constexpr int N1 = P + M;          // 2150
constexpr int N2 = P + DG;         // 4000
constexpr int E1 = 137600, E2 = 256000, EGP = 64000, EGM = 4800;
constexpr int SA_HID = 128;

// Edge-range offsets for the fused build kernel.
constexpr int HO1 = E1, HO2 = E1 + E2, HO3 = HO2 + EGP, HO4 = HO3 + EGP,
              HO5 = HO4 + EGM, HOE = HO5 + EGM;   // 531200 total edges

// ELL capacities (overflow list guarantees correctness regardless).
constexpr int CAP_A = 160;
constexpr int CAP_G = 96;
constexpr int OVF_CAP = 4096;

// One counter per 64B line (R7: removed same-line atomic serialization, 44->~35us).
constexpr int CPAD = 16;

// ---- fp16 helpers -----------------------------------------------------------
__device__ __forceinline__ float4 h4_to_f4(const __half* p) {
  union { ushort4 u4; __half2 h2[2]; } u;
  u.u4 = *(const ushort4*)p;
  float2 lo = __half22float2(u.h2[0]);
  float2 hi = __half22float2(u.h2[1]);
  return make_float4(lo.x, lo.y, hi.x, hi.y);
}
__device__ __forceinline__ void f4_to_h4(__half* p, float4 v) {
  union { ushort4 u4; __half2 h2[2]; } u;
  u.h2[0] = __float22half2_rn(make_float2(v.x, v.y));
  u.h2[1] = __float22half2_rn(make_float2(v.z, v.w));
  *(ushort4*)p = u.u4;
}

// ---------------------------------------------------------------------------
// ELL build (padded counters) + fused fp32->fp16 embed cast.
// ---------------------------------------------------------------------------
constexpr int CAST_CH = (P * F + M * F + DG * F) / 8;   // 8-float chunks

__global__ __launch_bounds__(256) void k_build(
    const int* __restrict__ a1r, const int* __restrict__ a1c, const float* __restrict__ a1v,
    const int* __restrict__ a2r, const int* __restrict__ a2c, const float* __restrict__ a2v,
    const int* __restrict__ d0, const int* __restrict__ s0,
    const int* __restrict__ d1, const int* __restrict__ s1,
    const int* __restrict__ d2, const int* __restrict__ s2,
    const int* __restrict__ d3, const int* __restrict__ s3,
    int* cur1, uint2* ell1, int* cur2, uint2* ell2,
    int* cu0, unsigned* eg0, int* cu1, unsigned* eg1,
    int* cu2, unsigned* eg2, int* cu3, unsigned* eg3,
    int* __restrict__ ovf_n, int4* __restrict__ ovf,
    const float* __restrict__ pEf, const float* __restrict__ mEf,
    const float* __restrict__ dEf,
    __half* __restrict__ pEh, __half* __restrict__ mEh, __half* __restrict__ dEh) {
  int tid = blockIdx.x * 256 + threadIdx.x;
  int T = gridDim.x * 256;
  int seg[4], row[4]; unsigned p0[4], p1[4];
#pragma unroll
  for (int u = 0; u < 4; ++u) {
    int i = tid + u * T;
    seg[u] = -1;
    if (i < HOE) {
      if (i < HO1)      { seg[u] = 0; row[u] = a1r[i]; p0[u] = (unsigned)a1c[i]; p1[u] = __float_as_uint(a1v[i]); }
      else if (i < HO2) { int j = i - HO1; seg[u] = 1; row[u] = a2r[j]; p0[u] = (unsigned)a2c[j]; p1[u] = __float_as_uint(a2v[j]); }
      else if (i < HO3) { int j = i - HO2; seg[u] = 2; row[u] = d0[j]; p0[u] = (unsigned)s0[j]; }
      else if (i < HO4) { int j = i - HO3; seg[u] = 3; row[u] = d1[j]; p0[u] = (unsigned)s1[j]; }
      else if (i < HO5) { int j = i - HO4; seg[u] = 4; row[u] = d2[j]; p0[u] = (unsigned)s2[j]; }
      else              { int j = i - HO5; seg[u] = 5; row[u] = d3[j]; p0[u] = (unsigned)s3[j]; }
    }
  }
#pragma unroll
  for (int u = 0; u < 4; ++u) {
    int r = row[u];
    switch (seg[u]) {
      case 0: { int slot = atomicAdd(&cur1[(size_t)r * CPAD], 1);
        if (slot < CAP_A) ell1[(size_t)r * CAP_A + slot] = make_uint2(p0[u], p1[u]);
        else { int o = atomicAdd(&ovf_n[0], 1); if (o < OVF_CAP) ovf[0 * OVF_CAP + o] = make_int4(r, (int)p0[u], (int)p1[u], 0); } } break;
      case 1: { int slot = atomicAdd(&cur2[(size_t)r * CPAD], 1);
        if (slot < CAP_A) ell2[(size_t)r * CAP_A + slot] = make_uint2(p0[u], p1[u]);
        else { int o = atomicAdd(&ovf_n[1], 1); if (o < OVF_CAP) ovf[1 * OVF_CAP + o] = make_int4(r, (int)p0[u], (int)p1[u], 0); } } break;
      case 2: { int slot = atomicAdd(&cu0[(size_t)r * CPAD], 1);
        if (slot < CAP_G) eg0[(size_t)r * CAP_G + slot] = p0[u];
        else { int o = atomicAdd(&ovf_n[2], 1); if (o < OVF_CAP) ovf[2 * OVF_CAP + o] = make_int4(r, (int)p0[u], 0, 0); } } break;
      case 3: { int slot = atomicAdd(&cu1[(size_t)r * CPAD], 1);
        if (slot < CAP_G) eg1[(size_t)r * CAP_G + slot] = p0[u];
        else { int o = atomicAdd(&ovf_n[3], 1); if (o < OVF_CAP) ovf[3 * OVF_CAP + o] = make_int4(r, (int)p0[u], 0, 0); } } break;
      case 4: { int slot = atomicAdd(&cu2[(size_t)r * CPAD], 1);
        if (slot < CAP_G) eg2[(size_t)r * CAP_G + slot] = p0[u];
        else { int o = atomicAdd(&ovf_n[4], 1); if (o < OVF_CAP) ovf[4 * OVF_CAP + o] = make_int4(r, (int)p0[u], 0, 0); } } break;
      case 5: { int slot = atomicAdd(&cu3[(size_t)r * CPAD], 1);
        if (slot < CAP_G) eg3[(size_t)r * CAP_G + slot] = p0[u];
        else { int o = atomicAdd(&ovf_n[5], 1); if (o < OVF_CAP) ovf[5 * OVF_CAP + o] = make_int4(r, (int)p0[u], 0, 0); } } break;
      default: break;
    }
  }
  // Fused embed cast fp32 -> fp16 (independent streaming work).
  for (int c = tid; c < CAST_CH; c += T) {
    int j = c * 8;
    const float* src; __half* dst;
    if (j < P * F)              { src = pEf + j;               dst = pEh + j; }
    else if (j < P * F + M * F) { src = mEf + (j - P * F);     dst = mEh + (j - P * F); }
    else                        { src = dEf + (j - P*F - M*F); dst = dEh + (j - P*F - M*F); }
    float4 a = *(const float4*)src, b = *(const float4*)(src + 4);
    f4_to_h4(dst, a);
    f4_to_h4(dst + 4, b);
  }
}

// ---------------------------------------------------------------------------
// SPMM: TWO waves per row (edges split by parity, LDS combine) -> 12.3K waves
// (48/CU) and half the per-wave dependent-gather chain. fp16 gathers, fp32
// accumulate. 6150 row-groups, 2 per 256-thread block (even split: 3075).
// ---------------------------------------------------------------------------
template<int LAYER>
__global__ __launch_bounds__(256) void k_spmm(
    const int* __restrict__ cur1, const uint2* __restrict__ ell1,
    const int* __restrict__ cur2, const uint2* __restrict__ ell2,
    const int* __restrict__ ovf_n, const int4* __restrict__ ovf,
    const __half* __restrict__ pEh, const __half* __restrict__ mEh,
    const __half* __restrict__ dEh,
    float* __restrict__ lat1f, float* __restrict__ lat2f,
    __half* __restrict__ lat1h, __half* __restrict__ lat2h,
    float* __restrict__ acc1, float* __restrict__ acc2,
    float* __restrict__ out_mgcn, float* __restrict__ out_dgcn) {
  int grp = (blockIdx.x * 256 + threadIdx.x) >> 7;   // row-group id
  int lane = threadIdx.x & 63;
  int wh   = (threadIdx.x >> 6) & 1;                 // wave-half within group
  int gl   = threadIdx.x >> 7;                       // group slot in block (0/1)
  bool g2 = grp >= N1;
  int row = g2 ? grp - N1 : grp;
  const uint2* pe = (g2 ? ell2 : ell1) + (size_t)row * CAP_A;
  const __half* latinh = g2 ? lat2h : lat1h;
  const __half* tailEh = g2 ? dEh : mEh;
  int deg = (g2 ? cur2 : cur1)[(size_t)row * CPAD];
  int dn = deg < CAP_A ? deg : CAP_A;
  int fo = lane << 2;
  float4 s = {0.f, 0.f, 0.f, 0.f};
  auto fetch = [&](int c) -> float4 {
    const __half* b;
    if (LAYER == 1) b = (c < P) ? (pEh + (size_t)c * F) : (tailEh + (size_t)(c - P) * F);
    else            b = latinh + (size_t)c * F;
    return h4_to_f4(b + fo);
  };
  // This wave handles edges wh, wh+2, wh+4, ... (independent parity stream).
  int i = wh;
  for (; i + 15 <= dn; i += 16) {    // 8 edges: i, i+2, ..., i+14
    uint2 m[8]; float4 a[8];
#pragma unroll
    for (int u = 0; u < 8; ++u) m[u] = pe[i + 2 * u];
#pragma unroll
    for (int u = 0; u < 8; ++u) a[u] = fetch((int)m[u].x);
#pragma unroll
    for (int u = 0; u < 8; ++u) {
      float v = __uint_as_float(m[u].y);
      s.x += v * a[u].x; s.y += v * a[u].y; s.z += v * a[u].z; s.w += v * a[u].w;
    }
  }
  for (; i < dn; i += 2) {
    uint2 m = pe[i];
    float v = __uint_as_float(m.y);
    float4 a = fetch((int)m.x);
    s.x += v * a.x; s.y += v * a.y; s.z += v * a.z; s.w += v * a.w;
  }
  // Combine the two parity partials via LDS (block-uniform control flow).
  __shared__ float part[2][F];
  if (wh == 1) *(float4*)&part[gl][fo] = s;
  __syncthreads();
  if (wh == 1) return;
  {
    float4 p = *(const float4*)&part[gl][fo];
    s.x += p.x; s.y += p.y; s.z += p.z; s.w += p.w;
  }
  // Overflow edges (normally zero), wave 0 only.
  {
    int gi = g2 ? 1 : 0;
    int on = ovf_n[gi];
    if (on > 0) {
      const int4* ol = ovf + gi * OVF_CAP;
      for (int k = 0; k < on; ++k) {
        int4 e = ol[k];
        if (e.x == row) {
          float v = __int_as_float(e.z);
          float4 a = fetch(e.y);
          s.x += v * a.x; s.y += v * a.y; s.z += v * a.z; s.w += v * a.w;
        }
      }
    }
  }
  float4 l;
  l.x = s.x > 0.f ? s.x : 0.5f * s.x;
  l.y = s.y > 0.f ? s.y : 0.5f * s.y;
  l.z = s.z > 0.f ? s.z : 0.5f * s.z;
  l.w = s.w > 0.f ? s.w : 0.5f * s.w;
  if (LAYER == 1) {
    *(float4*)((g2 ? lat2f : lat1f) + (size_t)row * F + fo) = l;   // exact own-row
    f4_to_h4((g2 ? lat2h : lat1h) + (size_t)row * F + fo, l);      // gather copy
  } else {
    const float* latf = g2 ? lat2f : lat1f;
    float4 b = *(const float4*)(latf + (size_t)row * F + fo);
    float4 a = {b.x + l.x, b.y + l.y, b.z + l.z, b.w + l.w};
    *(float4*)((g2 ? acc2 : acc1) + (size_t)row * F + fo) = a;
    if (row >= P)
      *(float4*)((g2 ? out_dgcn : out_mgcn) + (size_t)(row - P) * F + fo) = a;
  }
}

// ---------------------------------------------------------------------------
// All 4 GAT feature GEMMs. FR=8 (R8's FR=16 cut blocks to 270 -> 4 waves/CU
// and regressed; W is L2-resident so occupancy beats traffic reduction).
// ---------------------------------------------------------------------------
constexpr int FR  = 8;
constexpr int NB0 = (P + FR - 1) / FR;   // 250
constexpr int NB2 = (M + FR - 1) / FR;   // 19
constexpr int FEAT_BLOCKS = 2 * NB0 + 2 * NB2;

__global__ __launch_bounds__(256) void k_gat_feat_all(
    const float* __restrict__ acc1, const float* __restrict__ acc2,
    const float* __restrict__ gat_W, const float* __restrict__ gat_al,
    const float* __restrict__ gat_ar,
    __half* __restrict__ f0, __half* __restrict__ f1,
    __half* __restrict__ f2, __half* __restrict__ f3,
    float* __restrict__ el, float* __restrict__ er) {
  int b = blockIdx.x;
  int g, rb, n; const float* h; __half* fout;
  if (b < NB0)            { g = 0; rb = b;              n = P; h = acc1; fout = f0; }
  else if (b < 2 * NB0)   { g = 1; rb = b - NB0;        n = P; h = acc2; fout = f1; }
  else if (b < 2*NB0+NB2) { g = 2; rb = b - 2 * NB0;    n = M; h = acc1 + (size_t)P * F; fout = f2; }
  else                    { g = 3; rb = b - 2*NB0 - NB2; n = M; h = acc1 + (size_t)P * F; fout = f3; }
  int elo = (g == 0) ? 0 : (g == 1) ? P * H : (g == 2) ? 2 * P * H : (2 * P + M) * H;
  const float* W = gat_W + (size_t)g * F * F;
  __shared__ float hs[FR][F];
  int t = threadIdx.x;
  int r0 = rb * FR;
  for (int q = t; q < FR * 64; q += 256) {
    int r = q >> 6, ln = q & 63;
    int row = r0 + r;
    float4 v = {0.f, 0.f, 0.f, 0.f};
    if (row < n) v = *(const float4*)(h + (size_t)row * F + (ln << 2));
    *(float4*)&hs[r][ln << 2] = v;
  }
  __syncthreads();
  float acc[FR];
#pragma unroll
  for (int r = 0; r < FR; ++r) acc[r] = 0.f;
  for (int k = 0; k < F; k += 4) {
    float w0 = W[(size_t)k * F + t],       w1 = W[(size_t)(k + 1) * F + t],
          w2 = W[(size_t)(k + 2) * F + t], w3 = W[(size_t)(k + 3) * F + t];
#pragma unroll
    for (int r = 0; r < FR; ++r) {
      float4 h4 = *(const float4*)&hs[r][k];
      acc[r] += h4.x * w0 + h4.y * w1 + h4.z * w2 + h4.w * w3;
    }
  }
  int head = t >> 6, d = t & 63;           // one wave == one head
  float av = gat_al[g * H * DH + head * DH + d];
  float rv = gat_ar[g * H * DH + head * DH + d];
#pragma unroll
  for (int r = 0; r < FR; ++r) {
    int row = r0 + r;
    if (row < n) {
      fout[(size_t)row * F + t] = __float2half_rn(acc[r]);
      float cl = acc[r] * av, cr = acc[r] * rv;
      for (int o = 32; o > 0; o >>= 1) {
        cl += __shfl_down(cl, o, 64);
        cr += __shfl_down(cr, o, 64);
      }
      if (d == 0) { el[elo + row * H + head] = cl; er[elo + row * H + head] = cr; }
    }
  }
}

// ---------------------------------------------------------------------------
// All 4 GAT aggregations: wave-per-dst-row over ELL, fp16 feat gathers.
// ---------------------------------------------------------------------------
__global__ __launch_bounds__(256) void k_gat_agg_all(
    const int* __restrict__ cu0, const unsigned* __restrict__ eg0,
    const int* __restrict__ cu1, const unsigned* __restrict__ eg1,
    const int* __restrict__ cu2, const unsigned* __restrict__ eg2,
    const int* __restrict__ cu3, const unsigned* __restrict__ eg3,
    const int* __restrict__ ovf_n, const int4* __restrict__ ovf,
    const float* __restrict__ el, const float* __restrict__ er,
    const __half* __restrict__ f0, const __half* __restrict__ f1,
    const __half* __restrict__ f2, const __half* __restrict__ f3,
    const float* __restrict__ gat_b,
    float* __restrict__ e0, float* __restrict__ e1,
    float* __restrict__ e2, float* __restrict__ e3) {
  int gw = (blockIdx.x * 256 + threadIdx.x) >> 6;
  if (gw >= 2 * P + 2 * M) return;
  int lane = threadIdx.x & 63;
  int g, row; const int* cu; const unsigned* eg; const __half* feat; float* out; int elo;
  if (gw < P)            { g = 0; row = gw;             cu = cu0; eg = eg0; feat = f0; out = e0; elo = 0; }
  else if (gw < 2 * P)   { g = 1; row = gw - P;         cu = cu1; eg = eg1; feat = f1; out = e1; elo = P * H; }
  else if (gw < 2*P + M) { g = 2; row = gw - 2 * P;     cu = cu2; eg = eg2; feat = f2; out = e2; elo = 2 * P * H; }
  else                   { g = 3; row = gw - 2 * P - M; cu = cu3; eg = eg3; feat = f3; out = e3; elo = (2 * P + M) * H; }
  int head = lane >> 4;
  int fo = lane << 2;
  const float* elb = el + elo;
  float erv = er[elo + row * H + head];
  int deg = cu[(size_t)row * CPAD];
  int dn = deg < CAP_G ? deg : CAP_G;
  const unsigned* ps = eg + (size_t)row * CAP_G;
  int on = ovf_n[2 + g];
  const int4* ol = ovf + (2 + g) * OVF_CAP;
  float mx = -3.4e38f;
  int i = 0;
  for (; i + 4 <= dn; i += 4) {
    int s0 = (int)ps[i], s1 = (int)ps[i + 1], s2 = (int)ps[i + 2], s3 = (int)ps[i + 3];
    float a = elb[s0 * H + head] + erv, b = elb[s1 * H + head] + erv,
          c = elb[s2 * H + head] + erv, d = elb[s3 * H + head] + erv;
    a = a > 0.f ? a : 0.2f * a; b = b > 0.f ? b : 0.2f * b;
    c = c > 0.f ? c : 0.2f * c; d = d > 0.f ? d : 0.2f * d;
    mx = fmaxf(mx, fmaxf(fmaxf(a, b), fmaxf(c, d)));
  }
  for (; i < dn; ++i) {
    float a = elb[(int)ps[i] * H + head] + erv;
    a = a > 0.f ? a : 0.2f * a;
    mx = fmaxf(mx, a);
  }
  if (on > 0) {
    for (int k = 0; k < on; ++k) {
      int4 e = ol[k];
      if (e.x == row) {
        float a = elb[e.y * H + head] + erv;
        a = a > 0.f ? a : 0.2f * a;
        mx = fmaxf(mx, a);
      }
    }
  }
  float ssum = 0.f;
  float4 acc = {0.f, 0.f, 0.f, 0.f};
  i = 0;
  for (; i + 2 <= dn; i += 2) {
    int s0 = (int)ps[i], s1 = (int)ps[i + 1];
    float a = elb[s0 * H + head] + erv; a = a > 0.f ? a : 0.2f * a;
    float b = elb[s1 * H + head] + erv; b = b > 0.f ? b : 0.2f * b;
    float x0 = expf(a - mx), x1 = expf(b - mx);
    float4 q0 = h4_to_f4(feat + (size_t)s0 * F + fo);
    float4 q1 = h4_to_f4(feat + (size_t)s1 * F + fo);
    ssum += x0 + x1;
    acc.x += x0 * q0.x + x1 * q1.x;
    acc.y += x0 * q0.y + x1 * q1.y;
    acc.z += x0 * q0.z + x1 * q1.z;
    acc.w += x0 * q0.w + x1 * q1.w;
  }
  for (; i < dn; ++i) {
    int s0 = (int)ps[i];
    float a = elb[s0 * H + head] + erv; a = a > 0.f ? a : 0.2f * a;
    float x0 = expf(a - mx);
    float4 q0 = h4_to_f4(feat + (size_t)s0 * F + fo);
    ssum += x0;
    acc.x += x0 * q0.x; acc.y += x0 * q0.y; acc.z += x0 * q0.z; acc.w += x0 * q0.w;
  }
  if (on > 0) {
    for (int k = 0; k < on; ++k) {
      int4 e = ol[k];
      if (e.x == row) {
        float a = elb[e.y * H + head] + erv; a = a > 0.f ? a : 0.2f * a;
        float x0 = expf(a - mx);
        float4 q0 = h4_to_f4(feat + (size_t)e.y * F + fo);
        ssum += x0;
        acc.x += x0 * q0.x; acc.y += x0 * q0.y; acc.z += x0 * q0.z; acc.w += x0 * q0.w;
      }
    }
  }
  float inv = 1.f / (ssum + 1e-9f);
  const float* bb = gat_b + g * F + fo;
  float4 v = {acc.x * inv + bb[0], acc.y * inv + bb[1],
              acc.z * inv + bb[2], acc.w * inv + bb[3]};
  v.x = v.x > 0.f ? v.x : expm1f(v.x);
  v.y = v.y > 0.f ? v.y : expm1f(v.y);
  v.z = v.z > 0.f ? v.z : expm1f(v.z);
  v.w = v.w > 0.f ? v.w : expm1f(v.w);
  *(float4*)(out + (size_t)row * F + fo) = v;
}

// ---------------------------------------------------------------------------
// Semantic attention weights. SR=4 -> 1076 blocks (8.4 waves/CU vs 2.1 at
// SR=16); W1 re-reads are L2-resident so occupancy wins.
// ---------------------------------------------------------------------------
constexpr int SR  = 4;
constexpr int SB0 = (P + SR - 1) / SR;   // 500
constexpr int SB2 = (M + SR - 1) / SR;   // 38
constexpr int SEM_BLOCKS = 2 * SB0 + 2 * SB2;

__global__ __launch_bounds__(128) void k_sem_w_all(
    const float* __restrict__ e0, const float* __restrict__ e1,
    const float* __restrict__ e2, const float* __restrict__ e3,
    const float* __restrict__ W1, const float* __restrict__ b1,
    const float* __restrict__ W2, float* __restrict__ w) {
  int b = blockIdx.x;
  int zid, rb, n; const float* z;
  if (b < SB0)            { zid = 0; rb = b;             n = P; z = e0; }
  else if (b < 2 * SB0)   { zid = 1; rb = b - SB0;       n = P; z = e1; }
  else if (b < 2*SB0+SB2) { zid = 2; rb = b - 2 * SB0;   n = M; z = e2; }
  else                    { zid = 3; rb = b - 2*SB0-SB2; n = M; z = e3; }
  __shared__ float zs[SR][F];
  int t = threadIdx.x;
  int r0 = rb * SR;
  for (int q = t; q < SR * 64; q += 128) {
    int r = q >> 6, ln = q & 63;
    int row = r0 + r;
    float4 v = {0.f, 0.f, 0.f, 0.f};
    if (row < n) v = *(const float4*)(z + (size_t)row * F + (ln << 2));
    *(float4*)&zs[r][ln << 2] = v;
  }
  __syncthreads();
  float hid[SR];
#pragma unroll
  for (int r = 0; r < SR; ++r) hid[r] = b1[t];
  for (int k = 0; k < F; k += 4) {
    float w0 = W1[(size_t)k * SA_HID + t],       w1 = W1[(size_t)(k + 1) * SA_HID + t],
          w2 = W1[(size_t)(k + 2) * SA_HID + t], w3 = W1[(size_t)(k + 3) * SA_HID + t];
#pragma unroll
    for (int r = 0; r < SR; ++r) {
      float4 z4 = *(const float4*)&zs[r][k];
      hid[r] += z4.x * w0 + z4.y * w1 + z4.z * w2 + z4.w * w3;
    }
  }
  float w2v = W2[t];
  float local = 0.f;
  for (int r = 0; r < SR; ++r) {
    int row = r0 + r;
    if (row < n) local += tanhf(hid[r]) * w2v;
  }
  for (int o = 32; o > 0; o >>= 1) local += __shfl_down(local, o, 64);
  __shared__ float pp[2];
  if ((t & 63) == 0) pp[t >> 6] = local;
  __syncthreads();
  if (t == 0) atomicAdd(&w[zid], pp[0] + pp[1]);
}

// ---------------------------------------------------------------------------
// Single-block: med = beta-combine(e2,e3) + on-the-fly relu column-sum, then
// c[m2] = sv . W_bot[:,m2] + M*out_b[m2].
// ---------------------------------------------------------------------------
__global__ __launch_bounds__(256) void k_med_cvec(
    const float* __restrict__ e2, const float* __restrict__ e3,
    const float* __restrict__ w, const float* __restrict__ outW,
    const float* __restrict__ outb,
    float* __restrict__ out_med, float* __restrict__ cbuf) {
  int t = threadIdx.x;
  float m0 = w[2] * (1.f / M), m1 = w[3] * (1.f / M);
  float mxv = fmaxf(m0, m1);
  float a0 = expf(m0 - mxv), a1 = expf(m1 - mxv);
  float sc = 1.f / (a0 + a1);
  a0 *= sc; a1 *= sc;
  float4 rs = {0.f, 0.f, 0.f, 0.f};
  for (int j = t; j < M * F / 4; j += 256) {
    float4 u0 = ((const float4*)e2)[j], u1 = ((const float4*)e3)[j];
    float4 r = {a0 * u0.x + a1 * u1.x, a0 * u0.y + a1 * u1.y,
                a0 * u0.z + a1 * u1.z, a0 * u0.w + a1 * u1.w};
    ((float4*)out_med)[j] = r;
    rs.x += r.x > 0.f ? r.x : 0.f;
    rs.y += r.y > 0.f ? r.y : 0.f;
    rs.z += r.z > 0.f ? r.z : 0.f;
    rs.w += r.w > 0.f ? r.w : 0.f;
  }
  __shared__ float4 sv4[4][64];
  sv4[t >> 6][t & 63] = rs;
  __syncthreads();
  __shared__ float sv[F];
  if (t < 64) {
    float4 a = sv4[0][t], b = sv4[1][t], c = sv4[2][t], d = sv4[3][t];
    sv[t * 4 + 0] = a.x + b.x + c.x + d.x;
    sv[t * 4 + 1] = a.y + b.y + c.y + d.y;
    sv[t * 4 + 2] = a.z + b.z + c.z + d.z;
    sv[t * 4 + 3] = a.w + b.w + c.w + d.w;
  }
  __syncthreads();
  if (t < M) {
    float cc = (float)M * outb[t];
    for (int f = 0; f < F; f += 4) {
      cc += sv[f]     * outW[(size_t)(F + f) * M + t]
          + sv[f + 1] * outW[(size_t)(F + f + 1) * M + t]
          + sv[f + 2] * outW[(size_t)(F + f + 2) * M + t]
          + sv[f + 3] * outW[(size_t)(F + f + 3) * M + t];
    }
    cbuf[t] = cc;
  }
}

// ---------------------------------------------------------------------------
// Final: patient beta-combine fused with simi GEMM. FIN_R=4 -> 500 blocks.
// ---------------------------------------------------------------------------
constexpr int FIN_R = 4;   // P % FIN_R == 0
__global__ __launch_bounds__(256) void k_final(
    const float* __restrict__ e0, const float* __restrict__ e1,
    const float* __restrict__ w, const float* __restrict__ outW,
    const float* __restrict__ c,
    float* __restrict__ out_pat, float* __restrict__ simi) {
  float m0 = w[0] * (1.f / P), m1 = w[1] * (1.f / P);
  float mxv = fmaxf(m0, m1);
  float a0 = expf(m0 - mxv), a1 = expf(m1 - mxv);
  float sc = 1.f / (a0 + a1);
  a0 *= sc; a1 *= sc;
  __shared__ float psh[FIN_R][F];
  int t = threadIdx.x;
  int r0 = blockIdx.x * FIN_R;
  for (int q = t; q < FIN_R * 64; q += 256) {
    int r = q >> 6, ln = q & 63;
    size_t off = (size_t)(r0 + r) * F + (ln << 2);
    float4 u0 = *(const float4*)(e0 + off), u1 = *(const float4*)(e1 + off);
    float4 v = {a0 * u0.x + a1 * u1.x, a0 * u0.y + a1 * u1.y,
                a0 * u0.z + a1 * u1.z, a0 * u0.w + a1 * u1.w};
    *(float4*)(out_pat + off) = v;
    v.x = v.x > 0.f ? v.x : 0.f; v.y = v.y > 0.f ? v.y : 0.f;
    v.z = v.z > 0.f ? v.z : 0.f; v.w = v.w > 0.f ? v.w : 0.f;
    *(float4*)&psh[r][ln << 2] = v;
  }
  __syncthreads();
  if (t < M) {
    float acc[FIN_R];
#pragma unroll
    for (int r = 0; r < FIN_R; ++r) acc[r] = 0.f;
    for (int f = 0; f < F; f += 4) {
      float w0 = outW[(size_t)f * M + t],       w1 = outW[(size_t)(f + 1) * M + t],
            w2 = outW[(size_t)(f + 2) * M + t], w3 = outW[(size_t)(f + 3) * M + t];
#pragma unroll
      for (int r = 0; r < FIN_R; ++r) {
        float4 p4 = *(const float4*)&psh[r][f];
        acc[r] += p4.x * w0 + p4.y * w1 + p4.z * w2 + p4.w * w3;
      }
    }
    float cv = c[t];
    for (int r = 0; r < FIN_R; ++r)
      simi[(size_t)(r0 + r) * M + t] = (float)M * acc[r] + cv;
  }
}

// ---------------------------------------------------------------------------
extern "C" void kernel_launch(void* const* d_in, const int* in_sizes, int n_in,
                              void* d_out, int out_size, void* d_ws, size_t ws_size,
                              hipStream_t stream) {
  const int*   adj1_rows = (const int*)d_in[0];
  const int*   adj1_cols = (const int*)d_in[1];
  const float* adj1_vals = (const float*)d_in[2];
  const int*   adj2_rows = (const int*)d_in[3];
  const int*   adj2_cols = (const int*)d_in[4];
  const float* adj2_vals = (const float*)d_in[5];
  const int*   g0_src = (const int*)d_in[6];
  const int*   g0_dst = (const int*)d_in[7];
  const int*   g1_src = (const int*)d_in[8];
  const int*   g1_dst = (const int*)d_in[9];
  const int*   g2_src = (const int*)d_in[10];
  const int*   g2_dst = (const int*)d_in[11];
  const int*   g3_src = (const int*)d_in[12];
  const int*   g3_dst = (const int*)d_in[13];
  // d_in[14] = keepRate (unused, == 1)
  const float* pE     = (const float*)d_in[15];
  const float* mE     = (const float*)d_in[16];
  const float* dE     = (const float*)d_in[17];
  const float* gat_W  = (const float*)d_in[18];
  const float* gat_al = (const float*)d_in[19];
  const float* gat_ar = (const float*)d_in[20];
  const float* gat_b  = (const float*)d_in[21];
  const float* sa_W1  = (const float*)d_in[22];
  const float* sa_b1  = (const float*)d_in[23];
  const float* sa_W2  = (const float*)d_in[24];
  const float* out_W  = (const float*)d_in[25];
  const float* out_b  = (const float*)d_in[26];

  // ---- workspace layout: [zeroed (padded counters) | ELL | fp16 | fp32] ----
  int* ip = (int*)d_ws;
  int* cur1 = ip; ip += (size_t)N1 * CPAD;
  int* cur2 = ip; ip += (size_t)N2 * CPAD;
  int* cu0  = ip; ip += (size_t)P * CPAD;
  int* cu1  = ip; ip += (size_t)P * CPAD;
  int* cu2  = ip; ip += (size_t)M * CPAD;
  int* cu3  = ip; ip += (size_t)M * CPAD;
  int* ovf_n = ip; ip += 6;
  float* wbuf = (float*)ip; ip += 4;
  size_t memset_bytes = (size_t)((char*)ip - (char*)d_ws);

  uintptr_t up = ((uintptr_t)ip + 15) & ~(uintptr_t)15;
  int4* ovf = (int4*)up;                       // 6 * OVF_CAP
  uint2* ell1 = (uint2*)(ovf + 6 * OVF_CAP);   // N1 * CAP_A
  uint2* ell2 = ell1 + (size_t)N1 * CAP_A;     // N2 * CAP_A
  unsigned* eg0 = (unsigned*)(ell2 + (size_t)N2 * CAP_A);
  unsigned* eg1 = eg0 + (size_t)P * CAP_G;
  unsigned* eg2 = eg1 + (size_t)P * CAP_G;
  unsigned* eg3 = eg2 + (size_t)M * CAP_G;
  // fp16 region (16B-aligned by construction)
  __half* hp = (__half*)(eg3 + (size_t)M * CAP_G);
  __half* pEh   = hp; hp += (size_t)P * F;
  __half* mEh   = hp; hp += (size_t)M * F;
  __half* dEh   = hp; hp += (size_t)DG * F;
  __half* lat1h = hp; hp += (size_t)N1 * F;
  __half* lat2h = hp; hp += (size_t)N2 * F;
  __half* f0h   = hp; hp += (size_t)P * F;
  __half* f1h   = hp; hp += (size_t)P * F;
  __half* f2h   = hp; hp += (size_t)M * F;
  __half* f3h   = hp; hp += (size_t)M * F;
  float* fp = (float*)hp;
  float* lat1f = fp; fp += (size_t)N1 * F;
  float* lat2f = fp; fp += (size_t)N2 * F;
  float* acc1  = fp; fp += (size_t)N1 * F;
  float* acc2  = fp; fp += (size_t)N2 * F;
  float* el    = fp; fp += (size_t)(2 * P + 2 * M) * H;
  float* er    = fp; fp += (size_t)(2 * P + 2 * M) * H;
  float* e0b   = fp; fp += (size_t)P * F;
  float* e1b   = fp; fp += (size_t)P * F;
  float* e2b   = fp; fp += (size_t)M * F;
  float* e3b   = fp; fp += (size_t)M * F;
  float* cbuf  = fp; fp += 256;

  // ---- output layout: (simi_pm, d_gcn, med, m_gcn, patient) ----
  float* out_simi = (float*)d_out;               // P*M
  float* out_dgcn = out_simi + (size_t)P * M;    // DG*F
  float* out_med  = out_dgcn + (size_t)DG * F;   // M*F
  float* out_mgcn = out_med  + (size_t)M * F;    // M*F
  float* out_pat  = out_mgcn + (size_t)M * F;    // P*F

  // ---- zero padded counters (~540 KB) ----
  hipMemsetAsync(d_ws, 0, memset_bytes, stream);

  // ---- ELL build + fused fp16 embed cast: ONE dispatch ----
  int eb = ((HOE + 3) / 4 + 255) / 256;
  k_build<<<eb, 256, 0, stream>>>(adj1_rows, adj1_cols, adj1_vals,
                                  adj2_rows, adj2_cols, adj2_vals,
                                  g0_dst, g0_src, g1_dst, g1_src,
                                  g2_dst, g2_src, g3_dst, g3_src,
                                  cur1, ell1, cur2, ell2,
                                  cu0, eg0, cu1, eg1, cu2, eg2, cu3, eg3,
                                  ovf_n, ovf,
                                  pE, mE, dE, pEh, mEh, dEh);

  // ---- GNN: 2 layers, 2 waves per row (edge-parity split) ----
  int sb = (N1 + N2) / 2;   // 6150 groups * 128 threads / 256 = 3075 blocks
  k_spmm<1><<<sb, 256, 0, stream>>>(cur1, ell1, cur2, ell2, ovf_n, ovf,
                                    pEh, mEh, dEh, lat1f, lat2f, lat1h, lat2h,
                                    acc1, acc2, out_mgcn, out_dgcn);
  k_spmm<2><<<sb, 256, 0, stream>>>(cur1, ell1, cur2, ell2, ovf_n, ovf,
                                    pEh, mEh, dEh, lat1f, lat2f, lat1h, lat2h,
                                    acc1, acc2, out_mgcn, out_dgcn);

  // ---- 4 GATs: 2 dispatches ----
  k_gat_feat_all<<<FEAT_BLOCKS, 256, 0, stream>>>(acc1, acc2, gat_W, gat_al, gat_ar,
                                                  f0h, f1h, f2h, f3h, el, er);
  int ab = ((2 * P + 2 * M) * 64 + 255) / 256;
  k_gat_agg_all<<<ab, 256, 0, stream>>>(cu0, eg0, cu1, eg1, cu2, eg2, cu3, eg3,
                                        ovf_n, ovf, el, er, f0h, f1h, f2h, f3h, gat_b,
                                        e0b, e1b, e2b, e3b);

  // ---- semantic attention weights ----
  k_sem_w_all<<<SEM_BLOCKS, 128, 0, stream>>>(e0b, e1b, e2b, e3b, sa_W1, sa_b1, sa_W2, wbuf);

  // ---- med combine + cvec (single block) ----
  k_med_cvec<<<1, 256, 0, stream>>>(e2b, e3b, wbuf, out_W, out_b, out_med, cbuf);

  // ---- final: patient combine + simi GEMM fused ----
  k_final<<<P / FIN_R, 256, 0, stream>>>(e0b, e1b, wbuf, out_W, cbuf, out_pat, out_simi);
}

// Round 11
// 310.891 us; speedup vs baseline: 1.0279x; 1.0098x over previous
//
#include <hip/hip_runtime.h>
#include <hip/hip_fp16.h>
#include <cmath>
#include <cstdint>

// Problem constants (fixed by the reference).
constexpr int P  = 2000, M = 150, DG = 2000, F = 256, H = 4, DH = 64;
constexpr int N1 = P + M;          // 2150
constexpr int N2 = P + DG;         // 4000
constexpr int E1 = 137600, E2 = 256000, EGP = 64000, EGM = 4800;
constexpr int SA_HID = 128;

// Edge-range offsets for the fused build kernel.
constexpr int HO1 = E1, HO2 = E1 + E2, HO3 = HO2 + EGP, HO4 = HO3 + EGP,
              HO5 = HO4 + EGM, HOE = HO5 + EGM;   // 531200 total edges

// ELL capacities (overflow list guarantees correctness regardless).
constexpr int CAP_A = 160;
constexpr int CAP_G = 96;
constexpr int OVF_CAP = 4096;

// One counter per 64B line (R7: removed same-line atomic serialization).
constexpr int CPAD = 16;

// ---- fp16 helpers -----------------------------------------------------------
__device__ __forceinline__ float4 h4_to_f4(const __half* p) {
  union { ushort4 u4; __half2 h2[2]; } u;
  u.u4 = *(const ushort4*)p;
  float2 lo = __half22float2(u.h2[0]);
  float2 hi = __half22float2(u.h2[1]);
  return make_float4(lo.x, lo.y, hi.x, hi.y);
}
__device__ __forceinline__ void f4_to_h4(__half* p, float4 v) {
  union { ushort4 u4; __half2 h2[2]; } u;
  u.h2[0] = __float22half2_rn(make_float2(v.x, v.y));
  u.h2[1] = __float22half2_rn(make_float2(v.z, v.w));
  *(ushort4*)p = u.u4;
}

// ---------------------------------------------------------------------------
// ELL build (padded counters) + fused fp32->fp16 embed cast.
// ---------------------------------------------------------------------------
constexpr int CAST_CH = (P * F + M * F + DG * F) / 8;   // 8-float chunks

__global__ __launch_bounds__(256) void k_build(
    const int* __restrict__ a1r, const int* __restrict__ a1c, const float* __restrict__ a1v,
    const int* __restrict__ a2r, const int* __restrict__ a2c, const float* __restrict__ a2v,
    const int* __restrict__ d0, const int* __restrict__ s0,
    const int* __restrict__ d1, const int* __restrict__ s1,
    const int* __restrict__ d2, const int* __restrict__ s2,
    const int* __restrict__ d3, const int* __restrict__ s3,
    int* cur1, uint2* ell1, int* cur2, uint2* ell2,
    int* cu0, unsigned* eg0, int* cu1, unsigned* eg1,
    int* cu2, unsigned* eg2, int* cu3, unsigned* eg3,
    int* __restrict__ ovf_n, int4* __restrict__ ovf,
    const float* __restrict__ pEf, const float* __restrict__ mEf,
    const float* __restrict__ dEf,
    __half* __restrict__ pEh, __half* __restrict__ mEh, __half* __restrict__ dEh) {
  int tid = blockIdx.x * 256 + threadIdx.x;
  int T = gridDim.x * 256;
  int seg[4], row[4]; unsigned p0[4], p1[4];
#pragma unroll
  for (int u = 0; u < 4; ++u) {
    int i = tid + u * T;
    seg[u] = -1;
    if (i < HOE) {
      if (i < HO1)      { seg[u] = 0; row[u] = a1r[i]; p0[u] = (unsigned)a1c[i]; p1[u] = __float_as_uint(a1v[i]); }
      else if (i < HO2) { int j = i - HO1; seg[u] = 1; row[u] = a2r[j]; p0[u] = (unsigned)a2c[j]; p1[u] = __float_as_uint(a2v[j]); }
      else if (i < HO3) { int j = i - HO2; seg[u] = 2; row[u] = d0[j]; p0[u] = (unsigned)s0[j]; }
      else if (i < HO4) { int j = i - HO3; seg[u] = 3; row[u] = d1[j]; p0[u] = (unsigned)s1[j]; }
      else if (i < HO5) { int j = i - HO4; seg[u] = 4; row[u] = d2[j]; p0[u] = (unsigned)s2[j]; }
      else              { int j = i - HO5; seg[u] = 5; row[u] = d3[j]; p0[u] = (unsigned)s3[j]; }
    }
  }
#pragma unroll
  for (int u = 0; u < 4; ++u) {
    int r = row[u];
    switch (seg[u]) {
      case 0: { int slot = atomicAdd(&cur1[(size_t)r * CPAD], 1);
        if (slot < CAP_A) ell1[(size_t)r * CAP_A + slot] = make_uint2(p0[u], p1[u]);
        else { int o = atomicAdd(&ovf_n[0], 1); if (o < OVF_CAP) ovf[0 * OVF_CAP + o] = make_int4(r, (int)p0[u], (int)p1[u], 0); } } break;
      case 1: { int slot = atomicAdd(&cur2[(size_t)r * CPAD], 1);
        if (slot < CAP_A) ell2[(size_t)r * CAP_A + slot] = make_uint2(p0[u], p1[u]);
        else { int o = atomicAdd(&ovf_n[1], 1); if (o < OVF_CAP) ovf[1 * OVF_CAP + o] = make_int4(r, (int)p0[u], (int)p1[u], 0); } } break;
      case 2: { int slot = atomicAdd(&cu0[(size_t)r * CPAD], 1);
        if (slot < CAP_G) eg0[(size_t)r * CAP_G + slot] = p0[u];
        else { int o = atomicAdd(&ovf_n[2], 1); if (o < OVF_CAP) ovf[2 * OVF_CAP + o] = make_int4(r, (int)p0[u], 0, 0); } } break;
      case 3: { int slot = atomicAdd(&cu1[(size_t)r * CPAD], 1);
        if (slot < CAP_G) eg1[(size_t)r * CAP_G + slot] = p0[u];
        else { int o = atomicAdd(&ovf_n[3], 1); if (o < OVF_CAP) ovf[3 * OVF_CAP + o] = make_int4(r, (int)p0[u], 0, 0); } } break;
      case 4: { int slot = atomicAdd(&cu2[(size_t)r * CPAD], 1);
        if (slot < CAP_G) eg2[(size_t)r * CAP_G + slot] = p0[u];
        else { int o = atomicAdd(&ovf_n[4], 1); if (o < OVF_CAP) ovf[4 * OVF_CAP + o] = make_int4(r, (int)p0[u], 0, 0); } } break;
      case 5: { int slot = atomicAdd(&cu3[(size_t)r * CPAD], 1);
        if (slot < CAP_G) eg3[(size_t)r * CAP_G + slot] = p0[u];
        else { int o = atomicAdd(&ovf_n[5], 1); if (o < OVF_CAP) ovf[5 * OVF_CAP + o] = make_int4(r, (int)p0[u], 0, 0); } } break;
      default: break;
    }
  }
  // Fused embed cast fp32 -> fp16 (independent streaming work).
  for (int c = tid; c < CAST_CH; c += T) {
    int j = c * 8;
    const float* src; __half* dst;
    if (j < P * F)              { src = pEf + j;               dst = pEh + j; }
    else if (j < P * F + M * F) { src = mEf + (j - P * F);     dst = mEh + (j - P * F); }
    else                        { src = dEf + (j - P*F - M*F); dst = dEh + (j - P*F - M*F); }
    float4 a = *(const float4*)src, b = *(const float4*)(src + 4);
    f4_to_h4(dst, a);
    f4_to_h4(dst + 4, b);
  }
}

// ---------------------------------------------------------------------------
// SPMM: TWO waves per row (edges split by parity, LDS combine), fp16 gathers,
// fp32 accumulate (R9 structure, proven).
// ---------------------------------------------------------------------------
template<int LAYER>
__global__ __launch_bounds__(256) void k_spmm(
    const int* __restrict__ cur1, const uint2* __restrict__ ell1,
    const int* __restrict__ cur2, const uint2* __restrict__ ell2,
    const int* __restrict__ ovf_n, const int4* __restrict__ ovf,
    const __half* __restrict__ pEh, const __half* __restrict__ mEh,
    const __half* __restrict__ dEh,
    float* __restrict__ lat1f, float* __restrict__ lat2f,
    __half* __restrict__ lat1h, __half* __restrict__ lat2h,
    float* __restrict__ acc1, float* __restrict__ acc2,
    float* __restrict__ out_mgcn, float* __restrict__ out_dgcn) {
  int grp = (blockIdx.x * 256 + threadIdx.x) >> 7;   // row-group id
  int lane = threadIdx.x & 63;
  int wh   = (threadIdx.x >> 6) & 1;                 // wave-half within group
  int gl   = threadIdx.x >> 7;                       // group slot in block (0/1)
  bool g2 = grp >= N1;
  int row = g2 ? grp - N1 : grp;
  const uint2* pe = (g2 ? ell2 : ell1) + (size_t)row * CAP_A;
  const __half* latinh = g2 ? lat2h : lat1h;
  const __half* tailEh = g2 ? dEh : mEh;
  int deg = (g2 ? cur2 : cur1)[(size_t)row * CPAD];
  int dn = deg < CAP_A ? deg : CAP_A;
  int fo = lane << 2;
  float4 s = {0.f, 0.f, 0.f, 0.f};
  auto fetch = [&](int c) -> float4 {
    const __half* b;
    if (LAYER == 1) b = (c < P) ? (pEh + (size_t)c * F) : (tailEh + (size_t)(c - P) * F);
    else            b = latinh + (size_t)c * F;
    return h4_to_f4(b + fo);
  };
  int i = wh;
  for (; i + 15 <= dn; i += 16) {    // 8 edges: i, i+2, ..., i+14
    uint2 m[8]; float4 a[8];
#pragma unroll
    for (int u = 0; u < 8; ++u) m[u] = pe[i + 2 * u];
#pragma unroll
    for (int u = 0; u < 8; ++u) a[u] = fetch((int)m[u].x);
#pragma unroll
    for (int u = 0; u < 8; ++u) {
      float v = __uint_as_float(m[u].y);
      s.x += v * a[u].x; s.y += v * a[u].y; s.z += v * a[u].z; s.w += v * a[u].w;
    }
  }
  for (; i < dn; i += 2) {
    uint2 m = pe[i];
    float v = __uint_as_float(m.y);
    float4 a = fetch((int)m.x);
    s.x += v * a.x; s.y += v * a.y; s.z += v * a.z; s.w += v * a.w;
  }
  __shared__ float part[2][F];
  if (wh == 1) *(float4*)&part[gl][fo] = s;
  __syncthreads();
  if (wh == 1) return;
  {
    float4 p = *(const float4*)&part[gl][fo];
    s.x += p.x; s.y += p.y; s.z += p.z; s.w += p.w;
  }
  // Overflow edges (normally zero), wave 0 only.
  {
    int gi = g2 ? 1 : 0;
    int on = ovf_n[gi];
    if (on > 0) {
      const int4* ol = ovf + gi * OVF_CAP;
      for (int k = 0; k < on; ++k) {
        int4 e = ol[k];
        if (e.x == row) {
          float v = __int_as_float(e.z);
          float4 a = fetch(e.y);
          s.x += v * a.x; s.y += v * a.y; s.z += v * a.z; s.w += v * a.w;
        }
      }
    }
  }
  float4 l;
  l.x = s.x > 0.f ? s.x : 0.5f * s.x;
  l.y = s.y > 0.f ? s.y : 0.5f * s.y;
  l.z = s.z > 0.f ? s.z : 0.5f * s.z;
  l.w = s.w > 0.f ? s.w : 0.5f * s.w;
  if (LAYER == 1) {
    *(float4*)((g2 ? lat2f : lat1f) + (size_t)row * F + fo) = l;   // exact own-row
    f4_to_h4((g2 ? lat2h : lat1h) + (size_t)row * F + fo, l);      // gather copy
  } else {
    const float* latf = g2 ? lat2f : lat1f;
    float4 b = *(const float4*)(latf + (size_t)row * F + fo);
    float4 a = {b.x + l.x, b.y + l.y, b.z + l.z, b.w + l.w};
    *(float4*)((g2 ? acc2 : acc1) + (size_t)row * F + fo) = a;
    if (row >= P)
      *(float4*)((g2 ? out_dgcn : out_mgcn) + (size_t)(row - P) * F + fo) = a;
  }
}

// ---------------------------------------------------------------------------
// All 4 GAT feature GEMMs. FR=8 (R8/R9: occupancy beats W-traffic reduction;
// MFMA variant failed layout verification in R10 — scalar is the keeper).
// ---------------------------------------------------------------------------
constexpr int FR  = 8;
constexpr int NB0 = (P + FR - 1) / FR;   // 250
constexpr int NB2 = (M + FR - 1) / FR;   // 19
constexpr int FEAT_BLOCKS = 2 * NB0 + 2 * NB2;

__global__ __launch_bounds__(256) void k_gat_feat_all(
    const float* __restrict__ acc1, const float* __restrict__ acc2,
    const float* __restrict__ gat_W, const float* __restrict__ gat_al,
    const float* __restrict__ gat_ar,
    __half* __restrict__ f0, __half* __restrict__ f1,
    __half* __restrict__ f2, __half* __restrict__ f3,
    float* __restrict__ el, float* __restrict__ er) {
  int b = blockIdx.x;
  int g, rb, n; const float* h; __half* fout;
  if (b < NB0)            { g = 0; rb = b;              n = P; h = acc1; fout = f0; }
  else if (b < 2 * NB0)   { g = 1; rb = b - NB0;        n = P; h = acc2; fout = f1; }
  else if (b < 2*NB0+NB2) { g = 2; rb = b - 2 * NB0;    n = M; h = acc1 + (size_t)P * F; fout = f2; }
  else                    { g = 3; rb = b - 2*NB0 - NB2; n = M; h = acc1 + (size_t)P * F; fout = f3; }
  int elo = (g == 0) ? 0 : (g == 1) ? P * H : (g == 2) ? 2 * P * H : (2 * P + M) * H;
  const float* W = gat_W + (size_t)g * F * F;
  __shared__ float hs[FR][F];
  int t = threadIdx.x;
  int r0 = rb * FR;
  for (int q = t; q < FR * 64; q += 256) {
    int r = q >> 6, ln = q & 63;
    int row = r0 + r;
    float4 v = {0.f, 0.f, 0.f, 0.f};
    if (row < n) v = *(const float4*)(h + (size_t)row * F + (ln << 2));
    *(float4*)&hs[r][ln << 2] = v;
  }
  __syncthreads();
  float acc[FR];
#pragma unroll
  for (int r = 0; r < FR; ++r) acc[r] = 0.f;
  for (int k = 0; k < F; k += 4) {
    float w0 = W[(size_t)k * F + t],       w1 = W[(size_t)(k + 1) * F + t],
          w2 = W[(size_t)(k + 2) * F + t], w3 = W[(size_t)(k + 3) * F + t];
#pragma unroll
    for (int r = 0; r < FR; ++r) {
      float4 h4 = *(const float4*)&hs[r][k];
      acc[r] += h4.x * w0 + h4.y * w1 + h4.z * w2 + h4.w * w3;
    }
  }
  int head = t >> 6, d = t & 63;           // one wave == one head
  float av = gat_al[g * H * DH + head * DH + d];
  float rv = gat_ar[g * H * DH + head * DH + d];
#pragma unroll
  for (int r = 0; r < FR; ++r) {
    int row = r0 + r;
    if (row < n) {
      fout[(size_t)row * F + t] = __float2half_rn(acc[r]);
      float cl = acc[r] * av, cr = acc[r] * rv;
      for (int o = 32; o > 0; o >>= 1) {
        cl += __shfl_down(cl, o, 64);
        cr += __shfl_down(cr, o, 64);
      }
      if (d == 0) { el[elo + row * H + head] = cl; er[elo + row * H + head] = cr; }
    }
  }
}

// ---------------------------------------------------------------------------
// All 4 GAT aggregations: TWO waves per dst-row (edge-parity split, same
// pattern as k_spmm). Max pass combined via LDS (exact); sum/acc partials
// combined per-lane via LDS. fp16 feat gathers; ovf handled by wave 0.
// 4300 groups * 128 threads = 2150 blocks (exact, no bounds check).
// ---------------------------------------------------------------------------
__global__ __launch_bounds__(256) void k_gat_agg_all(
    const int* __restrict__ cu0, const unsigned* __restrict__ eg0,
    const int* __restrict__ cu1, const unsigned* __restrict__ eg1,
    const int* __restrict__ cu2, const unsigned* __restrict__ eg2,
    const int* __restrict__ cu3, const unsigned* __restrict__ eg3,
    const int* __restrict__ ovf_n, const int4* __restrict__ ovf,
    const float* __restrict__ el, const float* __restrict__ er,
    const __half* __restrict__ f0, const __half* __restrict__ f1,
    const __half* __restrict__ f2, const __half* __restrict__ f3,
    const float* __restrict__ gat_b,
    float* __restrict__ e0, float* __restrict__ e1,
    float* __restrict__ e2, float* __restrict__ e3) {
  int grp = (blockIdx.x * 256 + threadIdx.x) >> 7;
  int lane = threadIdx.x & 63;
  int wh   = (threadIdx.x >> 6) & 1;
  int gl   = threadIdx.x >> 7;
  int g, row; const int* cu; const unsigned* eg; const __half* feat; float* out; int elo;
  if (grp < P)            { g = 0; row = grp;             cu = cu0; eg = eg0; feat = f0; out = e0; elo = 0; }
  else if (grp < 2 * P)   { g = 1; row = grp - P;         cu = cu1; eg = eg1; feat = f1; out = e1; elo = P * H; }
  else if (grp < 2*P + M) { g = 2; row = grp - 2 * P;     cu = cu2; eg = eg2; feat = f2; out = e2; elo = 2 * P * H; }
  else                    { g = 3; row = grp - 2 * P - M; cu = cu3; eg = eg3; feat = f3; out = e3; elo = (2 * P + M) * H; }
  int head = lane >> 4;
  int fo = lane << 2;
  const float* elb = el + elo;
  float erv = er[elo + row * H + head];
  int deg = cu[(size_t)row * CPAD];
  int dn = deg < CAP_G ? deg : CAP_G;
  const unsigned* ps = eg + (size_t)row * CAP_G;
  int on = ovf_n[2 + g];
  const int4* ol = ovf + (2 + g) * OVF_CAP;
  // ---- pass 1: max over this wave's parity edges ----
  float mx = -3.4e38f;
  int i = wh;
  for (; i + 7 <= dn; i += 8) {     // 4 edges: i, i+2, i+4, i+6
    int s0 = (int)ps[i], s1 = (int)ps[i + 2], s2 = (int)ps[i + 4], s3 = (int)ps[i + 6];
    float a = elb[s0 * H + head] + erv, b = elb[s1 * H + head] + erv,
          c = elb[s2 * H + head] + erv, d = elb[s3 * H + head] + erv;
    a = a > 0.f ? a : 0.2f * a; b = b > 0.f ? b : 0.2f * b;
    c = c > 0.f ? c : 0.2f * c; d = d > 0.f ? d : 0.2f * d;
    mx = fmaxf(mx, fmaxf(fmaxf(a, b), fmaxf(c, d)));
  }
  for (; i < dn; i += 2) {
    float a = elb[(int)ps[i] * H + head] + erv;
    a = a > 0.f ? a : 0.2f * a;
    mx = fmaxf(mx, a);
  }
  if (wh == 0 && on > 0) {
    for (int k = 0; k < on; ++k) {
      int4 e = ol[k];
      if (e.x == row) {
        float a = elb[e.y * H + head] + erv;
        a = a > 0.f ? a : 0.2f * a;
        mx = fmaxf(mx, a);
      }
    }
  }
  __shared__ float mxs[2][2][64];
  mxs[gl][wh][lane] = mx;
  __syncthreads();
  mx = fmaxf(mxs[gl][0][lane], mxs[gl][1][lane]);
  // ---- pass 2: exp-sum + weighted aggregation over parity edges ----
  float ssum = 0.f;
  float4 acc = {0.f, 0.f, 0.f, 0.f};
  i = wh;
  for (; i + 3 <= dn; i += 4) {     // 2 edges: i, i+2
    int s0 = (int)ps[i], s1 = (int)ps[i + 2];
    float a = elb[s0 * H + head] + erv; a = a > 0.f ? a : 0.2f * a;
    float b = elb[s1 * H + head] + erv; b = b > 0.f ? b : 0.2f * b;
    float x0 = expf(a - mx), x1 = expf(b - mx);
    float4 q0 = h4_to_f4(feat + (size_t)s0 * F + fo);
    float4 q1 = h4_to_f4(feat + (size_t)s1 * F + fo);
    ssum += x0 + x1;
    acc.x += x0 * q0.x + x1 * q1.x;
    acc.y += x0 * q0.y + x1 * q1.y;
    acc.z += x0 * q0.z + x1 * q1.z;
    acc.w += x0 * q0.w + x1 * q1.w;
  }
  for (; i < dn; i += 2) {
    int s0 = (int)ps[i];
    float a = elb[s0 * H + head] + erv; a = a > 0.f ? a : 0.2f * a;
    float x0 = expf(a - mx);
    float4 q0 = h4_to_f4(feat + (size_t)s0 * F + fo);
    ssum += x0;
    acc.x += x0 * q0.x; acc.y += x0 * q0.y; acc.z += x0 * q0.z; acc.w += x0 * q0.w;
  }
  __shared__ float4 pacc[2][64];
  __shared__ float  pss[2][64];
  if (wh == 1) { pacc[gl][lane] = acc; pss[gl][lane] = ssum; }
  __syncthreads();
  if (wh == 1) return;
  {
    float4 pa = pacc[gl][lane];
    acc.x += pa.x; acc.y += pa.y; acc.z += pa.z; acc.w += pa.w;
    ssum += pss[gl][lane];
  }
  if (on > 0) {
    for (int k = 0; k < on; ++k) {
      int4 e = ol[k];
      if (e.x == row) {
        float a = elb[e.y * H + head] + erv; a = a > 0.f ? a : 0.2f * a;
        float x0 = expf(a - mx);
        float4 q0 = h4_to_f4(feat + (size_t)e.y * F + fo);
        ssum += x0;
        acc.x += x0 * q0.x; acc.y += x0 * q0.y; acc.z += x0 * q0.z; acc.w += x0 * q0.w;
      }
    }
  }
  float inv = 1.f / (ssum + 1e-9f);
  const float* bb = gat_b + g * F + fo;
  float4 v = {acc.x * inv + bb[0], acc.y * inv + bb[1],
              acc.z * inv + bb[2], acc.w * inv + bb[3]};
  v.x = v.x > 0.f ? v.x : expm1f(v.x);
  v.y = v.y > 0.f ? v.y : expm1f(v.y);
  v.z = v.z > 0.f ? v.z : expm1f(v.z);
  v.w = v.w > 0.f ? v.w : expm1f(v.w);
  *(float4*)(out + (size_t)row * F + fo) = v;
}

// ---------------------------------------------------------------------------
// Semantic attention weights. SR=4 (R9: occupancy beats W1-traffic).
// ---------------------------------------------------------------------------
constexpr int SR  = 4;
constexpr int SB0 = (P + SR - 1) / SR;   // 500
constexpr int SB2 = (M + SR - 1) / SR;   // 38
constexpr int SEM_BLOCKS = 2 * SB0 + 2 * SB2;

__global__ __launch_bounds__(128) void k_sem_w_all(
    const float* __restrict__ e0, const float* __restrict__ e1,
    const float* __restrict__ e2, const float* __restrict__ e3,
    const float* __restrict__ W1, const float* __restrict__ b1,
    const float* __restrict__ W2, float* __restrict__ w) {
  int b = blockIdx.x;
  int zid, rb, n; const float* z;
  if (b < SB0)            { zid = 0; rb = b;             n = P; z = e0; }
  else if (b < 2 * SB0)   { zid = 1; rb = b - SB0;       n = P; z = e1; }
  else if (b < 2*SB0+SB2) { zid = 2; rb = b - 2 * SB0;   n = M; z = e2; }
  else                    { zid = 3; rb = b - 2*SB0-SB2; n = M; z = e3; }
  __shared__ float zs[SR][F];
  int t = threadIdx.x;
  int r0 = rb * SR;
  for (int q = t; q < SR * 64; q += 128) {
    int r = q >> 6, ln = q & 63;
    int row = r0 + r;
    float4 v = {0.f, 0.f, 0.f, 0.f};
    if (row < n) v = *(const float4*)(z + (size_t)row * F + (ln << 2));
    *(float4*)&zs[r][ln << 2] = v;
  }
  __syncthreads();
  float hid[SR];
#pragma unroll
  for (int r = 0; r < SR; ++r) hid[r] = b1[t];
  for (int k = 0; k < F; k += 4) {
    float w0 = W1[(size_t)k * SA_HID + t],       w1 = W1[(size_t)(k + 1) * SA_HID + t],
          w2 = W1[(size_t)(k + 2) * SA_HID + t], w3 = W1[(size_t)(k + 3) * SA_HID + t];
#pragma unroll
    for (int r = 0; r < SR; ++r) {
      float4 z4 = *(const float4*)&zs[r][k];
      hid[r] += z4.x * w0 + z4.y * w1 + z4.z * w2 + z4.w * w3;
    }
  }
  float w2v = W2[t];
  float local = 0.f;
  for (int r = 0; r < SR; ++r) {
    int row = r0 + r;
    if (row < n) local += tanhf(hid[r]) * w2v;
  }
  for (int o = 32; o > 0; o >>= 1) local += __shfl_down(local, o, 64);
  __shared__ float pp[2];
  if ((t & 63) == 0) pp[t >> 6] = local;
  __syncthreads();
  if (t == 0) atomicAdd(&w[zid], pp[0] + pp[1]);
}

// ---------------------------------------------------------------------------
// Single-block: med = beta-combine(e2,e3) + on-the-fly relu column-sum, then
// c[m2] = sv . W_bot[:,m2] + M*out_b[m2].
// ---------------------------------------------------------------------------
__global__ __launch_bounds__(256) void k_med_cvec(
    const float* __restrict__ e2, const float* __restrict__ e3,
    const float* __restrict__ w, const float* __restrict__ outW,
    const float* __restrict__ outb,
    float* __restrict__ out_med, float* __restrict__ cbuf) {
  int t = threadIdx.x;
  float m0 = w[2] * (1.f / M), m1 = w[3] * (1.f / M);
  float mxv = fmaxf(m0, m1);
  float a0 = expf(m0 - mxv), a1 = expf(m1 - mxv);
  float sc = 1.f / (a0 + a1);
  a0 *= sc; a1 *= sc;
  float4 rs = {0.f, 0.f, 0.f, 0.f};
  for (int j = t; j < M * F / 4; j += 256) {
    float4 u0 = ((const float4*)e2)[j], u1 = ((const float4*)e3)[j];
    float4 r = {a0 * u0.x + a1 * u1.x, a0 * u0.y + a1 * u1.y,
                a0 * u0.z + a1 * u1.z, a0 * u0.w + a1 * u1.w};
    ((float4*)out_med)[j] = r;
    rs.x += r.x > 0.f ? r.x : 0.f;
    rs.y += r.y > 0.f ? r.y : 0.f;
    rs.z += r.z > 0.f ? r.z : 0.f;
    rs.w += r.w > 0.f ? r.w : 0.f;
  }
  __shared__ float4 sv4[4][64];
  sv4[t >> 6][t & 63] = rs;
  __syncthreads();
  __shared__ float sv[F];
  if (t < 64) {
    float4 a = sv4[0][t], b = sv4[1][t], c = sv4[2][t], d = sv4[3][t];
    sv[t * 4 + 0] = a.x + b.x + c.x + d.x;
    sv[t * 4 + 1] = a.y + b.y + c.y + d.y;
    sv[t * 4 + 2] = a.z + b.z + c.z + d.z;
    sv[t * 4 + 3] = a.w + b.w + c.w + d.w;
  }
  __syncthreads();
  if (t < M) {
    float cc = (float)M * outb[t];
    for (int f = 0; f < F; f += 4) {
      cc += sv[f]     * outW[(size_t)(F + f) * M + t]
          + sv[f + 1] * outW[(size_t)(F + f + 1) * M + t]
          + sv[f + 2] * outW[(size_t)(F + f + 2) * M + t]
          + sv[f + 3] * outW[(size_t)(F + f + 3) * M + t];
    }
    cbuf[t] = cc;
  }
}

// ---------------------------------------------------------------------------
// Final: patient beta-combine fused with simi GEMM. FIN_R=4 -> 500 blocks.
// ---------------------------------------------------------------------------
constexpr int FIN_R = 4;   // P % FIN_R == 0
__global__ __launch_bounds__(256) void k_final(
    const float* __restrict__ e0, const float* __restrict__ e1,
    const float* __restrict__ w, const float* __restrict__ outW,
    const float* __restrict__ c,
    float* __restrict__ out_pat, float* __restrict__ simi) {
  float m0 = w[0] * (1.f / P), m1 = w[1] * (1.f / P);
  float mxv = fmaxf(m0, m1);
  float a0 = expf(m0 - mxv), a1 = expf(m1 - mxv);
  float sc = 1.f / (a0 + a1);
  a0 *= sc; a1 *= sc;
  __shared__ float psh[FIN_R][F];
  int t = threadIdx.x;
  int r0 = blockIdx.x * FIN_R;
  for (int q = t; q < FIN_R * 64; q += 256) {
    int r = q >> 6, ln = q & 63;
    size_t off = (size_t)(r0 + r) * F + (ln << 2);
    float4 u0 = *(const float4*)(e0 + off), u1 = *(const float4*)(e1 + off);
    float4 v = {a0 * u0.x + a1 * u1.x, a0 * u0.y + a1 * u1.y,
                a0 * u0.z + a1 * u1.z, a0 * u0.w + a1 * u1.w};
    *(float4*)(out_pat + off) = v;
    v.x = v.x > 0.f ? v.x : 0.f; v.y = v.y > 0.f ? v.y : 0.f;
    v.z = v.z > 0.f ? v.z : 0.f; v.w = v.w > 0.f ? v.w : 0.f;
    *(float4*)&psh[r][ln << 2] = v;
  }
  __syncthreads();
  if (t < M) {
    float acc[FIN_R];
#pragma unroll
    for (int r = 0; r < FIN_R; ++r) acc[r] = 0.f;
    for (int f = 0; f < F; f += 4) {
      float w0 = outW[(size_t)f * M + t],       w1 = outW[(size_t)(f + 1) * M + t],
            w2 = outW[(size_t)(f + 2) * M + t], w3 = outW[(size_t)(f + 3) * M + t];
#pragma unroll
      for (int r = 0; r < FIN_R; ++r) {
        float4 p4 = *(const float4*)&psh[r][f];
        acc[r] += p4.x * w0 + p4.y * w1 + p4.z * w2 + p4.w * w3;
      }
    }
    float cv = c[t];
    for (int r = 0; r < FIN_R; ++r)
      simi[(size_t)(r0 + r) * M + t] = (float)M * acc[r] + cv;
  }
}

// ---------------------------------------------------------------------------
extern "C" void kernel_launch(void* const* d_in, const int* in_sizes, int n_in,
                              void* d_out, int out_size, void* d_ws, size_t ws_size,
                              hipStream_t stream) {
  const int*   adj1_rows = (const int*)d_in[0];
  const int*   adj1_cols = (const int*)d_in[1];
  const float* adj1_vals = (const float*)d_in[2];
  const int*   adj2_rows = (const int*)d_in[3];
  const int*   adj2_cols = (const int*)d_in[4];
  const float* adj2_vals = (const float*)d_in[5];
  const int*   g0_src = (const int*)d_in[6];
  const int*   g0_dst = (const int*)d_in[7];
  const int*   g1_src = (const int*)d_in[8];
  const int*   g1_dst = (const int*)d_in[9];
  const int*   g2_src = (const int*)d_in[10];
  const int*   g2_dst = (const int*)d_in[11];
  const int*   g3_src = (const int*)d_in[12];
  const int*   g3_dst = (const int*)d_in[13];
  // d_in[14] = keepRate (unused, == 1)
  const float* pE     = (const float*)d_in[15];
  const float* mE     = (const float*)d_in[16];
  const float* dE     = (const float*)d_in[17];
  const float* gat_W  = (const float*)d_in[18];
  const float* gat_al = (const float*)d_in[19];
  const float* gat_ar = (const float*)d_in[20];
  const float* gat_b  = (const float*)d_in[21];
  const float* sa_W1  = (const float*)d_in[22];
  const float* sa_b1  = (const float*)d_in[23];
  const float* sa_W2  = (const float*)d_in[24];
  const float* out_W  = (const float*)d_in[25];
  const float* out_b  = (const float*)d_in[26];

  // ---- workspace layout: [zeroed (padded counters) | ELL | fp16 | fp32] ----
  int* ip = (int*)d_ws;
  int* cur1 = ip; ip += (size_t)N1 * CPAD;
  int* cur2 = ip; ip += (size_t)N2 * CPAD;
  int* cu0  = ip; ip += (size_t)P * CPAD;
  int* cu1  = ip; ip += (size_t)P * CPAD;
  int* cu2  = ip; ip += (size_t)M * CPAD;
  int* cu3  = ip; ip += (size_t)M * CPAD;
  int* ovf_n = ip; ip += 6;
  float* wbuf = (float*)ip; ip += 4;
  size_t memset_bytes = (size_t)((char*)ip - (char*)d_ws);

  uintptr_t up = ((uintptr_t)ip + 15) & ~(uintptr_t)15;
  int4* ovf = (int4*)up;                       // 6 * OVF_CAP
  uint2* ell1 = (uint2*)(ovf + 6 * OVF_CAP);   // N1 * CAP_A
  uint2* ell2 = ell1 + (size_t)N1 * CAP_A;     // N2 * CAP_A
  unsigned* eg0 = (unsigned*)(ell2 + (size_t)N2 * CAP_A);
  unsigned* eg1 = eg0 + (size_t)P * CAP_G;
  unsigned* eg2 = eg1 + (size_t)P * CAP_G;
  unsigned* eg3 = eg2 + (size_t)M * CAP_G;
  // fp16 region (16B-aligned by construction)
  __half* hp = (__half*)(eg3 + (size_t)M * CAP_G);
  __half* pEh   = hp; hp += (size_t)P * F;
  __half* mEh   = hp; hp += (size_t)M * F;
  __half* dEh   = hp; hp += (size_t)DG * F;
  __half* lat1h = hp; hp += (size_t)N1 * F;
  __half* lat2h = hp; hp += (size_t)N2 * F;
  __half* f0h   = hp; hp += (size_t)P * F;
  __half* f1h   = hp; hp += (size_t)P * F;
  __half* f2h   = hp; hp += (size_t)M * F;
  __half* f3h   = hp; hp += (size_t)M * F;
  float* fp = (float*)hp;
  float* lat1f = fp; fp += (size_t)N1 * F;
  float* lat2f = fp; fp += (size_t)N2 * F;
  float* acc1  = fp; fp += (size_t)N1 * F;
  float* acc2  = fp; fp += (size_t)N2 * F;
  float* el    = fp; fp += (size_t)(2 * P + 2 * M) * H;
  float* er    = fp; fp += (size_t)(2 * P + 2 * M) * H;
  float* e0b   = fp; fp += (size_t)P * F;
  float* e1b   = fp; fp += (size_t)P * F;
  float* e2b   = fp; fp += (size_t)M * F;
  float* e3b   = fp; fp += (size_t)M * F;
  float* cbuf  = fp; fp += 256;

  // ---- output layout: (simi_pm, d_gcn, med, m_gcn, patient) ----
  float* out_simi = (float*)d_out;               // P*M
  float* out_dgcn = out_simi + (size_t)P * M;    // DG*F
  float* out_med  = out_dgcn + (size_t)DG * F;   // M*F
  float* out_mgcn = out_med  + (size_t)M * F;    // M*F
  float* out_pat  = out_mgcn + (size_t)M * F;    // P*F

  // ---- zero padded counters (~540 KB) ----
  hipMemsetAsync(d_ws, 0, memset_bytes, stream);

  // ---- ELL build + fused fp16 embed cast: ONE dispatch ----
  int eb = ((HOE + 3) / 4 + 255) / 256;
  k_build<<<eb, 256, 0, stream>>>(adj1_rows, adj1_cols, adj1_vals,
                                  adj2_rows, adj2_cols, adj2_vals,
                                  g0_dst, g0_src, g1_dst, g1_src,
                                  g2_dst, g2_src, g3_dst, g3_src,
                                  cur1, ell1, cur2, ell2,
                                  cu0, eg0, cu1, eg1, cu2, eg2, cu3, eg3,
                                  ovf_n, ovf,
                                  pE, mE, dE, pEh, mEh, dEh);

  // ---- GNN: 2 layers, 2 waves per row (edge-parity split) ----
  int sb = (N1 + N2) / 2;
  k_spmm<1><<<sb, 256, 0, stream>>>(cur1, ell1, cur2, ell2, ovf_n, ovf,
                                    pEh, mEh, dEh, lat1f, lat2f, lat1h, lat2h,
                                    acc1, acc2, out_mgcn, out_dgcn);
  k_spmm<2><<<sb, 256, 0, stream>>>(cur1, ell1, cur2, ell2, ovf_n, ovf,
                                    pEh, mEh, dEh, lat1f, lat2f, lat1h, lat2h,
                                    acc1, acc2, out_mgcn, out_dgcn);

  // ---- 4 GATs: scalar feature GEMM + 2-wave-split aggregation ----
  k_gat_feat_all<<<FEAT_BLOCKS, 256, 0, stream>>>(acc1, acc2, gat_W, gat_al, gat_ar,
                                                  f0h, f1h, f2h, f3h, el, er);
  int ab = (2 * P + 2 * M) / 2;   // 4300 groups * 128 threads / 256
  k_gat_agg_all<<<ab, 256, 0, stream>>>(cu0, eg0, cu1, eg1, cu2, eg2, cu3, eg3,
                                        ovf_n, ovf, el, er, f0h, f1h, f2h, f3h, gat_b,
                                        e0b, e1b, e2b, e3b);

  // ---- semantic attention weights ----
  k_sem_w_all<<<SEM_BLOCKS, 128, 0, stream>>>(e0b, e1b, e2b, e3b, sa_W1, sa_b1, sa_W2, wbuf);

  // ---- med combine + cvec (single block) ----
  k_med_cvec<<<1, 256, 0, stream>>>(e2b, e3b, wbuf, out_W, out_b, out_med, cbuf);

  // ---- final: patient combine + simi GEMM fused ----
  k_final<<<P / FIN_R, 256, 0, stream>>>(e0b, e1b, wbuf, out_W, cbuf, out_pat, out_simi);
}